// Round 1
// baseline (323.239 us; speedup 1.0000x reference)
//
#include <hip/hip_runtime.h>
#include <stdint.h>
#include <stddef.h>

#define DEV __device__ __forceinline__

typedef unsigned short u16;
typedef __attribute__((ext_vector_type(8))) __bf16 bf16x8;
typedef __attribute__((ext_vector_type(4))) float f32x4;
typedef __attribute__((ext_vector_type(8))) unsigned short u16x8;
typedef __attribute__((ext_vector_type(4))) unsigned short u16x4;

// ---------- helpers ----------
DEV u16 f2bf(float f) {
  uint32_t u = __builtin_bit_cast(uint32_t, f);
  u += 0x7fffu + ((u >> 16) & 1u);  // round-to-nearest-even
  return (u16)(u >> 16);
}
DEV float bf2f(u16 h) {
  uint32_t u = ((uint32_t)h) << 16;
  return __builtin_bit_cast(float, u);
}
DEV f32x4 mfma16(bf16x8 a, bf16x8 b, f32x4 c) {
  return __builtin_amdgcn_mfma_f32_16x16x32_bf16(a, b, c, 0, 0, 0);
}
DEV void ld_lds16(const void* g, void* l) {
  __builtin_amdgcn_global_load_lds((const __attribute__((address_space(1))) void*)g,
                                   (__attribute__((address_space(3))) void*)l, 16, 0, 0);
}

// ---------- f32 -> bf16 convert ----------
__global__ __launch_bounds__(256) void k_cvt(const float* __restrict__ src,
                                             u16* __restrict__ dst, int n) {
  int i = (blockIdx.x * 256 + threadIdx.x) * 4;
  if (i >= n) return;
  const float4 f = *(const float4*)(src + i);
  u16x4 o;
  o.x = f2bf(f.x); o.y = f2bf(f.y); o.z = f2bf(f.z); o.w = f2bf(f.w);
  *(u16x4*)(dst + i) = o;
}

// ---------- GEMM: C[M,N] = A[M,K] * B[N,K]^T  (bf16 in, bf16 or f32 out) ----------
// m97 recipe: 128x128 tile, BK=64, 4 waves in 2x2, 4x4 MFMA tiles/wave,
// global_load_lds width=16, 2-barrier K-loop.
template <bool OUT_F32>
__global__ __launch_bounds__(256) void k_gemm_bt(const u16* __restrict__ A,
                                                 const u16* __restrict__ B,
                                                 void* __restrict__ Cv,
                                                 int N, int K) {
  __shared__ __align__(16) u16 sA[128 * 64];
  __shared__ __align__(16) u16 sB[128 * 64];
  const int tid = threadIdx.x;
  const int lane = tid & 63;
  const int wid = tid >> 6;
  const int wm = wid & 1, wn = wid >> 1;
  const int col16 = lane & 15, quad = lane >> 4;
  const int rowBase = blockIdx.y * 128;
  const int colBase = blockIdx.x * 128;
  const int seg_r = lane >> 3;  // 0..7 row within 8-row segment
  const int seg_c = lane & 7;   // 0..7 16B chunk within row

  f32x4 zero; zero[0] = zero[1] = zero[2] = zero[3] = 0.0f;
  f32x4 acc[4][4];
#pragma unroll
  for (int i = 0; i < 4; ++i)
#pragma unroll
    for (int j = 0; j < 4; ++j) acc[i][j] = zero;

  for (int k0 = 0; k0 < K; k0 += 64) {
#pragma unroll
    for (int c = 0; c < 4; ++c) {
      const int seg = wid * 4 + c;  // wave-uniform
      const size_t ga = (size_t)(rowBase + seg * 8 + seg_r) * K + k0 + seg_c * 8;
      ld_lds16(A + ga, sA + seg * 512);
      const size_t gb = (size_t)(colBase + seg * 8 + seg_r) * K + k0 + seg_c * 8;
      ld_lds16(B + gb, sB + seg * 512);
    }
    __syncthreads();  // drains vmcnt (global_load_lds) + barrier
#pragma unroll
    for (int kk = 0; kk < 2; ++kk) {
      bf16x8 af[4], bfr[4];
#pragma unroll
      for (int t = 0; t < 4; ++t) {
        af[t]  = *(const bf16x8*)(sA + (wm * 64 + t * 16 + col16) * 64 + kk * 32 + quad * 8);
        bfr[t] = *(const bf16x8*)(sB + (wn * 64 + t * 16 + col16) * 64 + kk * 32 + quad * 8);
      }
#pragma unroll
      for (int tm = 0; tm < 4; ++tm)
#pragma unroll
        for (int tn = 0; tn < 4; ++tn)
          acc[tm][tn] = mfma16(af[tm], bfr[tn], acc[tm][tn]);
    }
    __syncthreads();  // protect LDS before next stage
  }

#pragma unroll
  for (int tm = 0; tm < 4; ++tm)
#pragma unroll
    for (int tn = 0; tn < 4; ++tn)
#pragma unroll
      for (int r = 0; r < 4; ++r) {
        const int row = rowBase + wm * 64 + tm * 16 + quad * 4 + r;
        const int col = colBase + wn * 64 + tn * 16 + col16;
        const float v = acc[tm][tn][r];
        if (OUT_F32) ((float*)Cv)[(size_t)row * N + col] = v;
        else         ((u16*)Cv)[(size_t)row * N + col] = f2bf(v);
      }
}

// ---------- 2D RoPE on q,k + relayout to (B*H, S, 64) ----------
__global__ __launch_bounds__(256) void k_rope(const u16* __restrict__ QKV,
                                              const int* __restrict__ row_ids,
                                              const int* __restrict__ col_ids,
                                              u16* __restrict__ Qh,
                                              u16* __restrict__ Kh) {
  const int t = blockIdx.x * 256 + threadIdx.x;  // < B*S*H*32 = 1572864
  const int p = t & 31;
  const int rest = t >> 5;       // (b*2048 + s)*12 + h
  const int h = rest % 12;
  const int bs = rest / 12;      // b*2048 + s
  const int s = bs & 2047;
  const int b = bs >> 11;
  const int f = p & 15;
  const int hs = p >> 4;         // 0: row-half (dims 0..31), 1: col-half (dims 32..63)
  const int pos = hs ? col_ids[s] : row_ids[s];
  // inv_freq = 10000^(-f/16)
  const float ang = (float)pos * expf(-(float)f * 0.5756462732485114f);
  float sn, cs;
  sincosf(ang, &sn, &cs);
  const int d1 = hs * 32 + f;
  const int d2 = d1 + 16;
  const size_t ibase = (size_t)bs * 2304 + h * 64;
  const size_t obase = (((size_t)b * 12 + h) * 2048 + s) * 64;
  {
    const float x1 = bf2f(QKV[ibase + d1]);
    const float x2 = bf2f(QKV[ibase + d2]);
    Qh[obase + d1] = f2bf(x1 * cs - x2 * sn);
    Qh[obase + d2] = f2bf(x2 * cs + x1 * sn);
  }
  {
    const float x1 = bf2f(QKV[ibase + 768 + d1]);
    const float x2 = bf2f(QKV[ibase + 768 + d2]);
    Kh[obase + d1] = f2bf(x1 * cs - x2 * sn);
    Kh[obase + d2] = f2bf(x2 * cs + x1 * sn);
  }
}

// ---------- V transpose to (B*H, 64, S) so PV B-frags are k-contiguous ----------
__global__ __launch_bounds__(256) void k_vtrans(const u16* __restrict__ QKV,
                                                u16* __restrict__ Vt) {
  __shared__ __align__(16) u16 tile[64][72];
  const int s0 = blockIdx.x * 64;
  const int bh = blockIdx.y;
  const int b = bh / 12, h = bh % 12;
  const int tid = threadIdx.x;
  const int rl = tid >> 2;        // 0..63
  const int cb = (tid & 3) * 16;  // 0,16,32,48
  const u16* src = QKV + ((size_t)b * 2048 + s0 + rl) * 2304 + 1536 + h * 64 + cb;
  const u16x8 v0 = *(const u16x8*)src;
  const u16x8 v1 = *(const u16x8*)(src + 8);
  *(u16x8*)&tile[rl][cb] = v0;
  *(u16x8*)&tile[rl][cb + 8] = v1;
  __syncthreads();
  u16x8 o0, o1;
#pragma unroll
  for (int j = 0; j < 8; ++j) {
    o0[j] = tile[cb + j][rl];
    o1[j] = tile[cb + 8 + j][rl];
  }
  u16* dst = Vt + ((size_t)bh * 64 + rl) * 2048 + s0 + cb;
  *(u16x8*)dst = o0;
  *(u16x8*)(dst + 8) = o1;
}

// ---------- flash attention, causal, bf16 MFMA ----------
// grid (S/64, B*H); 4 waves/block, each wave owns 16 q-rows; k-tiles of 64.
__global__ __launch_bounds__(256) void k_attn(const u16* __restrict__ Qh,
                                              const u16* __restrict__ Kh,
                                              const u16* __restrict__ Vt,
                                              u16* __restrict__ O) {
  __shared__ __align__(16) u16 sP[4][16][72];
  const int tid = threadIdx.x;
  const int lane = tid & 63;
  const int wid = tid >> 6;
  const int col16 = lane & 15;
  const int quad = lane >> 4;
  const int qt = blockIdx.x;
  const int bh = blockIdx.y;
  const int b = bh / 12, h = bh % 12;
  const int qw = qt * 64 + wid * 16;  // this wave's first q-row

  const u16* Qb = Qh + (size_t)bh * (2048 * 64);
  const u16* Kb = Kh + (size_t)bh * (2048 * 64);
  const u16* Vb = Vt + (size_t)bh * (64 * 2048);

  // Q A-frags: A[m=col16][k=quad*8+j], two K=32 steps
  const bf16x8 aQ0 = *(const bf16x8*)(Qb + (size_t)(qw + col16) * 64 + quad * 8);
  const bf16x8 aQ1 = *(const bf16x8*)(Qb + (size_t)(qw + col16) * 64 + 32 + quad * 8);

  f32x4 zero; zero[0] = zero[1] = zero[2] = zero[3] = 0.0f;
  f32x4 o[4];
  float m_r[4], l_r[4];
#pragma unroll
  for (int i = 0; i < 4; ++i) { o[i] = zero; m_r[i] = -1e30f; l_r[i] = 0.0f; }

  u16* sPw = &sP[wid][0][0];
  const int nkt = ((qw + 15) >> 6) + 1;

  for (int ki = 0; ki < nkt; ++ki) {
    asm volatile("" ::: "memory");  // keep this iter's LDS writes after last iter's reads
    const int kt = ki * 64;
    // ---- scores: S = Q * K^T (C-layout: row=quad*4+r, col=col16 per 16-tile)
    f32x4 sc[4];
#pragma unroll
    for (int tn = 0; tn < 4; ++tn) {
      const u16* kp = Kb + (size_t)(kt + tn * 16 + col16) * 64 + quad * 8;
      f32x4 a = zero;
      a = mfma16(aQ0, *(const bf16x8*)kp, a);
      a = mfma16(aQ1, *(const bf16x8*)(kp + 32), a);
      sc[tn] = a;
    }
    // ---- scale + causal mask
    const bool diag = (kt + 63 > qw);
#pragma unroll
    for (int tn = 0; tn < 4; ++tn)
#pragma unroll
      for (int r = 0; r < 4; ++r) {
        float v = sc[tn][r] * 0.125f;
        if (diag && (kt + tn * 16 + col16 > qw + quad * 4 + r)) v = -1e30f;
        sc[tn][r] = v;
      }
    // ---- online softmax stats (row lives on 16 lanes of a quad, reg=row%4)
    float mnew[4], alpha[4], rs[4];
#pragma unroll
    for (int r = 0; r < 4; ++r) {
      float v = fmaxf(fmaxf(sc[0][r], sc[1][r]), fmaxf(sc[2][r], sc[3][r]));
      v = fmaxf(v, __shfl_xor(v, 1, 64));
      v = fmaxf(v, __shfl_xor(v, 2, 64));
      v = fmaxf(v, __shfl_xor(v, 4, 64));
      v = fmaxf(v, __shfl_xor(v, 8, 64));
      const float mn = fmaxf(m_r[r], v);
      alpha[r] = __expf(m_r[r] - mn);
      m_r[r] = mn;
      mnew[r] = mn;
      rs[r] = 0.0f;
    }
    // ---- P = exp(S - m), C-layout -> LDS (bf16)
#pragma unroll
    for (int tn = 0; tn < 4; ++tn)
#pragma unroll
      for (int r = 0; r < 4; ++r) {
        const float p = __expf(sc[tn][r] - mnew[r]);
        rs[r] += p;
        sPw[(quad * 4 + r) * 72 + tn * 16 + col16] = f2bf(p);
      }
#pragma unroll
    for (int r = 0; r < 4; ++r) {
      float v = rs[r];
      v += __shfl_xor(v, 1, 64);
      v += __shfl_xor(v, 2, 64);
      v += __shfl_xor(v, 4, 64);
      v += __shfl_xor(v, 8, 64);
      l_r[r] = l_r[r] * alpha[r] + v;
    }
    asm volatile("s_waitcnt lgkmcnt(0)" ::: "memory");  // P visible before A-frag reads
    // ---- rescale O, then O += P * V
#pragma unroll
    for (int t = 0; t < 4; ++t)
#pragma unroll
      for (int r = 0; r < 4; ++r) o[t][r] *= alpha[r];
    const bf16x8 aP0 = *(const bf16x8*)(sPw + col16 * 72 + quad * 8);
    const bf16x8 aP1 = *(const bf16x8*)(sPw + col16 * 72 + 32 + quad * 8);
#pragma unroll
    for (int tn = 0; tn < 4; ++tn) {
      const u16* vp = Vb + (size_t)(tn * 16 + col16) * 2048 + kt + quad * 8;
      o[tn] = mfma16(aP0, *(const bf16x8*)vp, o[tn]);
      o[tn] = mfma16(aP1, *(const bf16x8*)(vp + 32), o[tn]);
    }
  }

  float invl[4];
#pragma unroll
  for (int r = 0; r < 4; ++r) invl[r] = 1.0f / l_r[r];
#pragma unroll
  for (int tn = 0; tn < 4; ++tn)
#pragma unroll
    for (int r = 0; r < 4; ++r) {
      const size_t row = (size_t)b * 2048 + qw + quad * 4 + r;
      O[row * 768 + h * 64 + tn * 16 + col16] = f2bf(o[tn][r] * invl[r]);
    }
}

// ---------- launch ----------
extern "C" void kernel_launch(void* const* d_in, const int* in_sizes, int n_in,
                              void* d_out, int out_size, void* d_ws, size_t ws_size,
                              hipStream_t stream) {
  const float* x       = (const float*)d_in[0];
  const int*   row_ids = (const int*)d_in[1];
  const int*   col_ids = (const int*)d_in[2];
  const float* Wq      = (const float*)d_in[3];
  const float* Wk      = (const float*)d_in[4];
  const float* Wv      = (const float*)d_in[5];
  const float* Wo      = (const float*)d_in[6];
  float* out = (float*)d_out;

  uint8_t* w8 = (uint8_t*)d_ws;
  // byte offsets (all 256-aligned)
  u16* x_bf = (u16*)(w8 + 0);         // 4096x768      (6291456 B)
  u16* wqkv = (u16*)(w8 + 6291456);   // 2304x768      (3538944 B)
  u16* wo   = (u16*)(w8 + 9830400);   // 768x768       (1179648 B)
  u16* qkv  = (u16*)(w8 + 11010048);  // 4096x2304     (18874368 B)
  u16* qh   = (u16*)(w8 + 29884416);  // (24,2048,64)  (6291456 B)
  u16* kh   = (u16*)(w8 + 36175872);  // (24,2048,64)
  u16* vt   = (u16*)(w8 + 42467328);  // (24,64,2048)
  u16* obuf = (u16*)(w8 + 48758784);  // 4096x768

  // 1) convert to bf16
  k_cvt<<<3072, 256, 0, stream>>>(x, x_bf, 3145728);
  k_cvt<<<576, 256, 0, stream>>>(Wq, wqkv,           589824);
  k_cvt<<<576, 256, 0, stream>>>(Wk, wqkv + 589824,  589824);
  k_cvt<<<576, 256, 0, stream>>>(Wv, wqkv + 1179648, 589824);
  k_cvt<<<576, 256, 0, stream>>>(Wo, wo, 589824);
  // 2) fused QKV projection: (4096x768) @ (2304x768)^T -> 4096x2304 bf16
  k_gemm_bt<false><<<dim3(18, 32), 256, 0, stream>>>(x_bf, wqkv, (void*)qkv, 2304, 768);
  // 3) RoPE(q,k) + relayout; V transpose
  k_rope<<<6144, 256, 0, stream>>>(qkv, row_ids, col_ids, qh, kh);
  k_vtrans<<<dim3(32, 24), 256, 0, stream>>>(qkv, vt);
  // 4) causal flash attention -> (B,S,768) bf16
  k_attn<<<dim3(32, 24), 256, 0, stream>>>(qh, kh, vt, obuf);
  // 5) output projection -> f32
  k_gemm_bt<true><<<dim3(6, 32), 256, 0, stream>>>(obuf, wo, (void*)out, 768, 768);
}

// Round 2
// 319.849 us; speedup vs baseline: 1.0106x; 1.0106x over previous
//
#include <hip/hip_runtime.h>
#include <stdint.h>
#include <stddef.h>

#define DEV __device__ __forceinline__

typedef unsigned short u16;
typedef __attribute__((ext_vector_type(8))) __bf16 bf16x8;
typedef __attribute__((ext_vector_type(4))) float f32x4;
typedef __attribute__((ext_vector_type(8))) unsigned short u16x8;
typedef __attribute__((ext_vector_type(4))) unsigned short u16x4;

// ---------- helpers ----------
DEV u16 f2bf(float f) {
  uint32_t u = __builtin_bit_cast(uint32_t, f);
  u += 0x7fffu + ((u >> 16) & 1u);  // round-to-nearest-even
  return (u16)(u >> 16);
}
DEV float bf2f(u16 h) {
  uint32_t u = ((uint32_t)h) << 16;
  return __builtin_bit_cast(float, u);
}
DEV f32x4 mfma16(bf16x8 a, bf16x8 b, f32x4 c) {
  return __builtin_amdgcn_mfma_f32_16x16x32_bf16(a, b, c, 0, 0, 0);
}
DEV void ld_lds16(const void* g, void* l) {
  __builtin_amdgcn_global_load_lds((const __attribute__((address_space(1))) void*)g,
                                   (__attribute__((address_space(3))) void*)l, 16, 0, 0);
}

// ---------- f32 -> bf16 convert ----------
__global__ __launch_bounds__(256) void k_cvt(const float* __restrict__ src,
                                             u16* __restrict__ dst, int n) {
  int i = (blockIdx.x * 256 + threadIdx.x) * 4;
  if (i >= n) return;
  const float4 f = *(const float4*)(src + i);
  u16x4 o;
  o.x = f2bf(f.x); o.y = f2bf(f.y); o.z = f2bf(f.z); o.w = f2bf(f.w);
  *(u16x4*)(dst + i) = o;
}

// all four weights in one launch: grid (576, 4)
__global__ __launch_bounds__(256) void k_cvtw(const float* __restrict__ wq,
                                              const float* __restrict__ wk,
                                              const float* __restrict__ wv,
                                              const float* __restrict__ wo,
                                              u16* __restrict__ dqkv,
                                              u16* __restrict__ dwo) {
  const int w = blockIdx.y;
  const float* src = (w == 0) ? wq : (w == 1) ? wk : (w == 2) ? wv : wo;
  u16* dst = (w < 3) ? (dqkv + (size_t)w * 589824) : dwo;
  const int i = (blockIdx.x * 256 + threadIdx.x) * 4;
  const float4 f = *(const float4*)(src + i);
  u16x4 o;
  o.x = f2bf(f.x); o.y = f2bf(f.y); o.z = f2bf(f.z); o.w = f2bf(f.w);
  *(u16x4*)(dst + i) = o;
}

// ---------- GEMM: C[M,N] = A[M,K] * B[N,K]^T  (bf16 in, bf16 or f32 out) ----------
// m97 recipe: 128x128 tile, BK=64, 4 waves in 2x2, 4x4 MFMA tiles/wave,
// global_load_lds width=16, 2-barrier K-loop.
template <bool OUT_F32>
__global__ __launch_bounds__(256) void k_gemm_bt(const u16* __restrict__ A,
                                                 const u16* __restrict__ B,
                                                 void* __restrict__ Cv,
                                                 int N, int K) {
  __shared__ __align__(16) u16 sA[128 * 64];
  __shared__ __align__(16) u16 sB[128 * 64];
  const int tid = threadIdx.x;
  const int lane = tid & 63;
  const int wid = tid >> 6;
  const int wm = wid & 1, wn = wid >> 1;
  const int col16 = lane & 15, quad = lane >> 4;
  const int rowBase = blockIdx.y * 128;
  const int colBase = blockIdx.x * 128;
  const int seg_r = lane >> 3;  // 0..7 row within 8-row segment
  const int seg_c = lane & 7;   // 0..7 16B chunk within row

  f32x4 zero; zero[0] = zero[1] = zero[2] = zero[3] = 0.0f;
  f32x4 acc[4][4];
#pragma unroll
  for (int i = 0; i < 4; ++i)
#pragma unroll
    for (int j = 0; j < 4; ++j) acc[i][j] = zero;

  for (int k0 = 0; k0 < K; k0 += 64) {
#pragma unroll
    for (int c = 0; c < 4; ++c) {
      const int seg = wid * 4 + c;  // wave-uniform
      const size_t ga = (size_t)(rowBase + seg * 8 + seg_r) * K + k0 + seg_c * 8;
      ld_lds16(A + ga, sA + seg * 512);
      const size_t gb = (size_t)(colBase + seg * 8 + seg_r) * K + k0 + seg_c * 8;
      ld_lds16(B + gb, sB + seg * 512);
    }
    __syncthreads();  // drains vmcnt (global_load_lds) + barrier
#pragma unroll
    for (int kk = 0; kk < 2; ++kk) {
      bf16x8 af[4], bfr[4];
#pragma unroll
      for (int t = 0; t < 4; ++t) {
        af[t]  = *(const bf16x8*)(sA + (wm * 64 + t * 16 + col16) * 64 + kk * 32 + quad * 8);
        bfr[t] = *(const bf16x8*)(sB + (wn * 64 + t * 16 + col16) * 64 + kk * 32 + quad * 8);
      }
#pragma unroll
      for (int tm = 0; tm < 4; ++tm)
#pragma unroll
        for (int tn = 0; tn < 4; ++tn)
          acc[tm][tn] = mfma16(af[tm], bfr[tn], acc[tm][tn]);
    }
    __syncthreads();  // protect LDS before next stage
  }

#pragma unroll
  for (int tm = 0; tm < 4; ++tm)
#pragma unroll
    for (int tn = 0; tn < 4; ++tn)
#pragma unroll
      for (int r = 0; r < 4; ++r) {
        const int row = rowBase + wm * 64 + tm * 16 + quad * 4 + r;
        const int col = colBase + wn * 64 + tn * 16 + col16;
        const float v = acc[tm][tn][r];
        if (OUT_F32) ((float*)Cv)[(size_t)row * N + col] = v;
        else         ((u16*)Cv)[(size_t)row * N + col] = f2bf(v);
      }
}

// ---------- 2D RoPE on q,k + relayout to (B*H, S, 64) ----------
__global__ __launch_bounds__(256) void k_rope(const u16* __restrict__ QKV,
                                              const int* __restrict__ row_ids,
                                              const int* __restrict__ col_ids,
                                              u16* __restrict__ Qh,
                                              u16* __restrict__ Kh) {
  const int t = blockIdx.x * 256 + threadIdx.x;  // < B*S*H*32 = 1572864
  const int p = t & 31;
  const int rest = t >> 5;       // (b*2048 + s)*12 + h
  const int h = rest % 12;
  const int bs = rest / 12;      // b*2048 + s
  const int s = bs & 2047;
  const int b = bs >> 11;
  const int f = p & 15;
  const int hs = p >> 4;         // 0: row-half (dims 0..31), 1: col-half (dims 32..63)
  const int pos = hs ? col_ids[s] : row_ids[s];
  // inv_freq = 10000^(-f/16)
  const float ang = (float)pos * expf(-(float)f * 0.5756462732485114f);
  float sn, cs;
  sincosf(ang, &sn, &cs);
  const int d1 = hs * 32 + f;
  const int d2 = d1 + 16;
  const size_t ibase = (size_t)bs * 2304 + h * 64;
  const size_t obase = (((size_t)b * 12 + h) * 2048 + s) * 64;
  {
    const float x1 = bf2f(QKV[ibase + d1]);
    const float x2 = bf2f(QKV[ibase + d2]);
    Qh[obase + d1] = f2bf(x1 * cs - x2 * sn);
    Qh[obase + d2] = f2bf(x2 * cs + x1 * sn);
  }
  {
    const float x1 = bf2f(QKV[ibase + 768 + d1]);
    const float x2 = bf2f(QKV[ibase + 768 + d2]);
    Kh[obase + d1] = f2bf(x1 * cs - x2 * sn);
    Kh[obase + d2] = f2bf(x2 * cs + x1 * sn);
  }
}

// ---------- V transpose to (B*H, 64, S) so PV A-frags are k-contiguous ----------
__global__ __launch_bounds__(256) void k_vtrans(const u16* __restrict__ QKV,
                                                u16* __restrict__ Vt) {
  __shared__ __align__(16) u16 tile[64][72];
  const int s0 = blockIdx.x * 64;
  const int bh = blockIdx.y;
  const int b = bh / 12, h = bh % 12;
  const int tid = threadIdx.x;
  const int rl = tid >> 2;        // 0..63
  const int cb = (tid & 3) * 16;  // 0,16,32,48
  const u16* src = QKV + ((size_t)b * 2048 + s0 + rl) * 2304 + 1536 + h * 64 + cb;
  const u16x8 v0 = *(const u16x8*)src;
  const u16x8 v1 = *(const u16x8*)(src + 8);
  *(u16x8*)&tile[rl][cb] = v0;
  *(u16x8*)&tile[rl][cb + 8] = v1;
  __syncthreads();
  u16x8 o0, o1;
#pragma unroll
  for (int j = 0; j < 8; ++j) {
    o0[j] = tile[cb + j][rl];
    o1[j] = tile[cb + 8 + j][rl];
  }
  u16* dst = Vt + ((size_t)bh * 64 + rl) * 2048 + s0 + cb;
  *(u16x8*)dst = o0;
  *(u16x8*)(dst + 8) = o1;
}

// ---------- flash attention, causal, bf16 MFMA, transposed-score form ----------
// grid (S/64, B*H); 4 waves/block, each wave owns 16 q-rows; k-tiles of 64.
// Computes S^T = K*Q^T and O^T = V^T*P^T (operand-order swap of the same frags)
// so softmax stats are per-lane scalars (qrow = lane&15) and reductions are
// 2 shuffles instead of 16 per tile.
__global__ __launch_bounds__(256) void k_attn(const u16* __restrict__ Qh,
                                              const u16* __restrict__ Kh,
                                              const u16* __restrict__ Vt,
                                              u16* __restrict__ O) {
  __shared__ __align__(16) u16 sP[4][16][72];
  const int tid = threadIdx.x;
  const int lane = tid & 63;
  const int wid = tid >> 6;
  const int col16 = lane & 15;
  const int quad = lane >> 4;
  const int qt = gridDim.x - 1 - blockIdx.x;  // longest blocks dispatch first
  const int bh = blockIdx.y;
  const int b = bh / 12, h = bh % 12;
  const int qw = qt * 64 + wid * 16;  // this wave's first q-row

  const u16* Qb = Qh + (size_t)bh * (2048 * 64);
  const u16* Kb = Kh + (size_t)bh * (2048 * 64);
  const u16* Vb = Vt + (size_t)bh * (64 * 2048);

  // Q B-frags: B[n=qrow=col16][k=quad*8+j], two K=32 steps
  const bf16x8 bQ0 = *(const bf16x8*)(Qb + (size_t)(qw + col16) * 64 + quad * 8);
  const bf16x8 bQ1 = *(const bf16x8*)(Qb + (size_t)(qw + col16) * 64 + 32 + quad * 8);

  f32x4 zero; zero[0] = zero[1] = zero[2] = zero[3] = 0.0f;
  f32x4 o[4];  // O^T accumulators: row d = tn*16+quad*4+r, col qrow = col16
#pragma unroll
  for (int i = 0; i < 4; ++i) o[i] = zero;
  float m_r = -1e30f, l_r = 0.0f;  // per-lane: qrow = qw + col16

  u16* sPw = &sP[wid][0][0];
  const int nkt = ((qw + 15) >> 6) + 1;

  bf16x8 ka0[4], ka1[4], kb0[4], kb1[4];
#pragma unroll
  for (int tn = 0; tn < 4; ++tn) {
    const u16* kp = Kb + (size_t)(tn * 16 + col16) * 64 + quad * 8;
    ka0[tn] = *(const bf16x8*)kp;
    ka1[tn] = *(const bf16x8*)(kp + 32);
  }

  auto body = [&](int ki, bf16x8 (&ck0)[4], bf16x8 (&ck1)[4],
                  bf16x8 (&nk0)[4], bf16x8 (&nk1)[4]) {
    asm volatile("" ::: "memory");
    const int kt = ki * 64;
    // ---- V frags for this tile: issue early so latency hides under S^T+softmax
    bf16x8 vf0[4], vf1[4];
#pragma unroll
    for (int tn = 0; tn < 4; ++tn) {
      const u16* vp = Vb + (size_t)(tn * 16 + col16) * 2048 + kt + quad * 8;
      vf0[tn] = *(const bf16x8*)vp;
      vf1[tn] = *(const bf16x8*)(vp + 32);
    }
    // ---- S^T = K*Q^T  (C-layout: row kcol = tn*16+quad*4+r, col qrow = col16)
    f32x4 sc[4];
#pragma unroll
    for (int tn = 0; tn < 4; ++tn) {
      f32x4 a = zero;
      a = mfma16(ck0[tn], bQ0, a);
      a = mfma16(ck1[tn], bQ1, a);
      sc[tn] = a;
    }
    // ---- prefetch next K tile during softmax
    if (ki + 1 < nkt) {
      const int kt2 = kt + 64;
#pragma unroll
      for (int tn = 0; tn < 4; ++tn) {
        const u16* kp = Kb + (size_t)(kt2 + tn * 16 + col16) * 64 + quad * 8;
        nk0[tn] = *(const bf16x8*)kp;
        nk1[tn] = *(const bf16x8*)(kp + 32);
      }
    }
    // ---- scale + causal mask (kcol_global > qrow_global)
    const bool diag = (kt + 63 > qw);
#pragma unroll
    for (int tn = 0; tn < 4; ++tn)
#pragma unroll
      for (int r = 0; r < 4; ++r) {
        float v = sc[tn][r] * 0.125f;
        if (diag && (kt + tn * 16 + quad * 4 + r > qw + col16)) v = -1e30f;
        sc[tn][r] = v;
      }
    // ---- row max: 15 in-lane fmax + 2 shuffles (over quads)
    float vm = sc[0][0];
#pragma unroll
    for (int tn = 0; tn < 4; ++tn)
#pragma unroll
      for (int r = 0; r < 4; ++r) vm = fmaxf(vm, sc[tn][r]);
    vm = fmaxf(vm, __shfl_xor(vm, 16, 64));
    vm = fmaxf(vm, __shfl_xor(vm, 32, 64));
    const float mn = fmaxf(m_r, vm);
    const float alpha = __expf(m_r - mn);
    m_r = mn;
    // ---- P = exp(S - m): in-lane, pack bf16 pairs -> LDS as P[qrow][kcol]
    float rs = 0.0f;
#pragma unroll
    for (int tn = 0; tn < 4; ++tn)
#pragma unroll
      for (int h2 = 0; h2 < 2; ++h2) {
        const float p0 = __expf(sc[tn][2 * h2] - mn);
        const float p1 = __expf(sc[tn][2 * h2 + 1] - mn);
        rs += p0 + p1;
        const uint32_t w = (uint32_t)f2bf(p0) | ((uint32_t)f2bf(p1) << 16);
        ((uint32_t*)sPw)[col16 * 36 + tn * 8 + quad * 2 + h2] = w;
      }
    rs += __shfl_xor(rs, 16, 64);
    rs += __shfl_xor(rs, 32, 64);
    l_r = l_r * alpha + rs;
    // ---- rescale O^T (alpha is per-lane scalar)
#pragma unroll
    for (int t = 0; t < 4; ++t)
#pragma unroll
      for (int r = 0; r < 4; ++r) o[t][r] *= alpha;
    asm volatile("s_waitcnt lgkmcnt(0)" ::: "memory");  // P visible before frag reads
    // ---- P^T B-frags from LDS, O^T += V^T * P^T
    const bf16x8 bP0 = *(const bf16x8*)(sPw + col16 * 72 + quad * 8);
    const bf16x8 bP1 = *(const bf16x8*)(sPw + col16 * 72 + 32 + quad * 8);
#pragma unroll
    for (int tn = 0; tn < 4; ++tn) {
      o[tn] = mfma16(vf0[tn], bP0, o[tn]);
      o[tn] = mfma16(vf1[tn], bP1, o[tn]);
    }
  };

  for (int ki = 0; ki < nkt;) {
    body(ki, ka0, ka1, kb0, kb1);
    ++ki;
    if (ki >= nkt) break;
    body(ki, kb0, kb1, ka0, ka1);
    ++ki;
  }

  // ---- epilogue: normalize, store O^T (lane holds d = tn*16+quad*4+r, qrow = col16)
  const float invl = 1.0f / l_r;
  const size_t row = (size_t)b * 2048 + qw + col16;
#pragma unroll
  for (int tn = 0; tn < 4; ++tn)
#pragma unroll
    for (int h2 = 0; h2 < 2; ++h2) {
      const float v0 = o[tn][2 * h2] * invl;
      const float v1 = o[tn][2 * h2 + 1] * invl;
      const uint32_t w = (uint32_t)f2bf(v0) | ((uint32_t)f2bf(v1) << 16);
      const int col = h * 64 + tn * 16 + quad * 4 + 2 * h2;
      *(uint32_t*)(O + row * 768 + col) = w;
    }
}

// ---------- launch ----------
extern "C" void kernel_launch(void* const* d_in, const int* in_sizes, int n_in,
                              void* d_out, int out_size, void* d_ws, size_t ws_size,
                              hipStream_t stream) {
  const float* x       = (const float*)d_in[0];
  const int*   row_ids = (const int*)d_in[1];
  const int*   col_ids = (const int*)d_in[2];
  const float* Wq      = (const float*)d_in[3];
  const float* Wk      = (const float*)d_in[4];
  const float* Wv      = (const float*)d_in[5];
  const float* Wo      = (const float*)d_in[6];
  float* out = (float*)d_out;

  uint8_t* w8 = (uint8_t*)d_ws;
  u16* x_bf = (u16*)(w8 + 0);         // 4096x768      (6291456 B)
  u16* wqkv = (u16*)(w8 + 6291456);   // 2304x768      (3538944 B)
  u16* wo   = (u16*)(w8 + 9830400);   // 768x768       (1179648 B)
  u16* qkv  = (u16*)(w8 + 11010048);  // 4096x2304     (18874368 B)
  u16* qh   = (u16*)(w8 + 29884416);  // (24,2048,64)  (6291456 B)
  u16* kh   = (u16*)(w8 + 36175872);  // (24,2048,64)
  u16* vt   = (u16*)(w8 + 42467328);  // (24,64,2048)
  u16* obuf = (u16*)(w8 + 48758784);  // 4096x768

  // 1) convert to bf16
  k_cvt<<<3072, 256, 0, stream>>>(x, x_bf, 3145728);
  k_cvtw<<<dim3(576, 4), 256, 0, stream>>>(Wq, Wk, Wv, Wo, wqkv, wo);
  // 2) fused QKV projection: (4096x768) @ (2304x768)^T -> 4096x2304 bf16
  k_gemm_bt<false><<<dim3(18, 32), 256, 0, stream>>>(x_bf, wqkv, (void*)qkv, 2304, 768);
  // 3) RoPE(q,k) + relayout; V transpose
  k_rope<<<6144, 256, 0, stream>>>(qkv, row_ids, col_ids, qh, kh);
  k_vtrans<<<dim3(32, 24), 256, 0, stream>>>(qkv, vt);
  // 4) causal flash attention -> (B,S,768) bf16
  k_attn<<<dim3(32, 24), 256, 0, stream>>>(qh, kh, vt, obuf);
  // 5) output projection -> f32
  k_gemm_bt<true><<<dim3(6, 32), 256, 0, stream>>>(obuf, wo, (void*)out, 768, 768);
}

// Round 3
// 207.048 us; speedup vs baseline: 1.5612x; 1.5448x over previous
//
#include <hip/hip_runtime.h>
#include <stdint.h>
#include <stddef.h>

#define DEV __device__ __forceinline__

typedef unsigned short u16;
typedef __attribute__((ext_vector_type(8))) __bf16 bf16x8;
typedef __attribute__((ext_vector_type(4))) float f32x4;
typedef __attribute__((ext_vector_type(8))) unsigned short u16x8;
typedef __attribute__((ext_vector_type(4))) unsigned short u16x4;

// ---------- helpers ----------
DEV u16 f2bf(float f) {
  uint32_t u = __builtin_bit_cast(uint32_t, f);
  u += 0x7fffu + ((u >> 16) & 1u);  // round-to-nearest-even
  return (u16)(u >> 16);
}
DEV float bf2f(u16 h) {
  uint32_t u = ((uint32_t)h) << 16;
  return __builtin_bit_cast(float, u);
}
DEV f32x4 mfma16(bf16x8 a, bf16x8 b, f32x4 c) {
  return __builtin_amdgcn_mfma_f32_16x16x32_bf16(a, b, c, 0, 0, 0);
}
DEV void ld_lds16(const void* g, void* l) {
  __builtin_amdgcn_global_load_lds((const __attribute__((address_space(1))) void*)g,
                                   (__attribute__((address_space(3))) void*)l, 16, 0, 0);
}

// ---------- f32 -> bf16 convert, all 5 tensors in one launch ----------
// grid: 3072 (x) + 4*576 (weights) = 5376 blocks
__global__ __launch_bounds__(256) void k_cvt_all(const float* __restrict__ x,
                                                 const float* __restrict__ wq,
                                                 const float* __restrict__ wk,
                                                 const float* __restrict__ wv,
                                                 const float* __restrict__ wo,
                                                 u16* __restrict__ dx,
                                                 u16* __restrict__ dqkv,
                                                 u16* __restrict__ dwo) {
  const int bid = blockIdx.x;
  const float* src;
  u16* dst;
  int off;
  if (bid < 3072) {
    src = x; dst = dx; off = bid;
  } else {
    const int t = bid - 3072;
    const int w = t / 576;
    off = t - w * 576;
    src = (w == 0) ? wq : (w == 1) ? wk : (w == 2) ? wv : wo;
    dst = (w < 3) ? (dqkv + (size_t)w * 589824) : dwo;
  }
  const int i = (off * 256 + threadIdx.x) * 4;
  const float4 f = *(const float4*)(src + i);
  u16x4 o;
  o.x = f2bf(f.x); o.y = f2bf(f.y); o.z = f2bf(f.z); o.w = f2bf(f.w);
  *(u16x4*)(dst + i) = o;
}

// ---------- GEMM: C[M,N] = A[M,K] * B[N,K]^T, 64x128 tile ----------
// m97 recipe, M-tile 64 for better CU balance on short-M / small-grid cases.
// 4 waves side-by-side in N (each 64x32), 4x2 MFMA tiles/wave.
template <bool OUT_F32>
__global__ __launch_bounds__(256, 4) void k_gemm64(const u16* __restrict__ A,
                                                   const u16* __restrict__ B,
                                                   void* __restrict__ Cv,
                                                   int N, int K) {
  __shared__ __align__(16) u16 sA[64 * 64];
  __shared__ __align__(16) u16 sB[128 * 64];
  const int tid = threadIdx.x;
  const int lane = tid & 63;
  const int wid = tid >> 6;
  const int col16 = lane & 15, quad = lane >> 4;
  const int rowBase = blockIdx.y * 64;
  const int colBase = blockIdx.x * 128;
  const int seg_r = lane >> 3;
  const int seg_c = lane & 7;

  f32x4 zero; zero[0] = zero[1] = zero[2] = zero[3] = 0.0f;
  f32x4 acc[4][2];
#pragma unroll
  for (int i = 0; i < 4; ++i) { acc[i][0] = zero; acc[i][1] = zero; }

  for (int k0 = 0; k0 < K; k0 += 64) {
#pragma unroll
    for (int c = 0; c < 2; ++c) {
      const int seg = wid * 2 + c;
      ld_lds16(A + (size_t)(rowBase + seg * 8 + seg_r) * K + k0 + seg_c * 8, sA + seg * 512);
    }
#pragma unroll
    for (int c = 0; c < 4; ++c) {
      const int seg = wid * 4 + c;
      ld_lds16(B + (size_t)(colBase + seg * 8 + seg_r) * K + k0 + seg_c * 8, sB + seg * 512);
    }
    __syncthreads();
#pragma unroll
    for (int kk = 0; kk < 2; ++kk) {
      bf16x8 af[4], bfr[2];
#pragma unroll
      for (int t = 0; t < 4; ++t)
        af[t] = *(const bf16x8*)(sA + (t * 16 + col16) * 64 + kk * 32 + quad * 8);
#pragma unroll
      for (int t = 0; t < 2; ++t)
        bfr[t] = *(const bf16x8*)(sB + (wid * 32 + t * 16 + col16) * 64 + kk * 32 + quad * 8);
#pragma unroll
      for (int tm = 0; tm < 4; ++tm)
#pragma unroll
        for (int tn = 0; tn < 2; ++tn)
          acc[tm][tn] = mfma16(af[tm], bfr[tn], acc[tm][tn]);
    }
    __syncthreads();
  }

#pragma unroll
  for (int tm = 0; tm < 4; ++tm)
#pragma unroll
    for (int tn = 0; tn < 2; ++tn)
#pragma unroll
      for (int r = 0; r < 4; ++r) {
        const int row = rowBase + tm * 16 + quad * 4 + r;
        const int col = colBase + wid * 32 + tn * 16 + col16;
        const float v = acc[tm][tn][r];
        if (OUT_F32) ((float*)Cv)[(size_t)row * N + col] = v;
        else         ((u16*)Cv)[(size_t)row * N + col] = f2bf(v);
      }
}

// ---------- fused: 2D RoPE relayout (blocks 0..6143) + V transpose (6144..6911) ----------
__global__ __launch_bounds__(256) void k_rope_vtrans(const u16* __restrict__ QKV,
                                                     const int* __restrict__ row_ids,
                                                     const int* __restrict__ col_ids,
                                                     u16* __restrict__ Qh,
                                                     u16* __restrict__ Kh,
                                                     u16* __restrict__ Vt) {
  __shared__ __align__(16) u16 tile[64][72];
  if (blockIdx.x < 6144) {
    const int t = blockIdx.x * 256 + threadIdx.x;  // < B*S*H*32
    const int p = t & 31;
    const int rest = t >> 5;
    const int h = rest % 12;
    const int bs = rest / 12;
    const int s = bs & 2047;
    const int b = bs >> 11;
    const int f = p & 15;
    const int hs = p >> 4;
    const int pos = hs ? col_ids[s] : row_ids[s];
    const float ang = (float)pos * expf(-(float)f * 0.5756462732485114f);
    float sn, cs;
    sincosf(ang, &sn, &cs);
    const int d1 = hs * 32 + f;
    const int d2 = d1 + 16;
    const size_t ibase = (size_t)bs * 2304 + h * 64;
    const size_t obase = (((size_t)b * 12 + h) * 2048 + s) * 64;
    {
      const float x1 = bf2f(QKV[ibase + d1]);
      const float x2 = bf2f(QKV[ibase + d2]);
      Qh[obase + d1] = f2bf(x1 * cs - x2 * sn);
      Qh[obase + d2] = f2bf(x2 * cs + x1 * sn);
    }
    {
      const float x1 = bf2f(QKV[ibase + 768 + d1]);
      const float x2 = bf2f(QKV[ibase + 768 + d2]);
      Kh[obase + d1] = f2bf(x1 * cs - x2 * sn);
      Kh[obase + d2] = f2bf(x2 * cs + x1 * sn);
    }
  } else {
    const int vb = blockIdx.x - 6144;
    const int s0 = (vb & 31) * 64;
    const int bh = vb >> 5;
    const int b = bh / 12, h = bh % 12;
    const int tid = threadIdx.x;
    const int rl = tid >> 2;
    const int cb = (tid & 3) * 16;
    const u16* src = QKV + ((size_t)b * 2048 + s0 + rl) * 2304 + 1536 + h * 64 + cb;
    const u16x8 v0 = *(const u16x8*)src;
    const u16x8 v1 = *(const u16x8*)(src + 8);
    *(u16x8*)&tile[rl][cb] = v0;
    *(u16x8*)&tile[rl][cb + 8] = v1;
    __syncthreads();
    u16x8 o0, o1;
#pragma unroll
    for (int j = 0; j < 8; ++j) {
      o0[j] = tile[cb + j][rl];
      o1[j] = tile[cb + 8 + j][rl];
    }
    u16* dst = Vt + ((size_t)bh * 64 + rl) * 2048 + s0 + cb;
    *(u16x8*)dst = o0;
    *(u16x8*)(dst + 8) = o1;
  }
}

// ---------- flash attention, causal, bf16 MFMA ----------
// Transposed-score form (S^T = K*Q^T, O^T = V^T*P^T) + cooperative LDS staging:
// the block's 4 waves share one double-buffered 64-wide K/V tile loaded via
// global_load_lds (16B), single barrier per tile. XCD swizzle: blockIdx%8 picks
// the head group so each XCD's L2 serves only 3 heads (~2.3 MB < 4 MB).
__global__ __launch_bounds__(256, 3) void k_attn(const u16* __restrict__ Qh,
                                                 const u16* __restrict__ Kh,
                                                 const u16* __restrict__ Vt,
                                                 u16* __restrict__ O) {
  __shared__ __align__(16) u16 sK[2][64 * 64];
  __shared__ __align__(16) u16 sV[2][64 * 64];
  __shared__ __align__(16) u16 sP[4][16 * 72];
  const int tid = threadIdx.x;
  const int lane = tid & 63;
  const int wid = tid >> 6;
  const int col16 = lane & 15;
  const int quad = lane >> 4;
  // swizzle: XCD = blockIdx%8 -> same 3 heads per XCD; longest q-tiles first
  const int fIdx = blockIdx.x;
  const int b3 = fIdx & 7;
  const int r = fIdx >> 3;        // 0..95
  const int g = r >> 5;           // 0..2
  const int qt = 31 - (r & 31);
  const int bh = b3 + 8 * g;      // 0..23
  const int b = bh / 12, h = bh % 12;
  const int qw = qt * 64 + wid * 16;
  const int nkt = qt + 1;         // same for all 4 waves -> barrier-safe

  const u16* Qb = Qh + (size_t)bh * (2048 * 64);
  const u16* Kb = Kh + (size_t)bh * (2048 * 64);
  const u16* Vb = Vt + (size_t)bh * (64 * 2048);

  // Q B-frags: B[n=qrow=col16][k=quad*8+j], two K=32 steps
  const bf16x8 bQ0 = *(const bf16x8*)(Qb + (size_t)(qw + col16) * 64 + quad * 8);
  const bf16x8 bQ1 = *(const bf16x8*)(Qb + (size_t)(qw + col16) * 64 + 32 + quad * 8);

  f32x4 zero; zero[0] = zero[1] = zero[2] = zero[3] = 0.0f;
  f32x4 o[4];  // O^T: row d = tn*16+quad*4+r, col qrow = col16
#pragma unroll
  for (int i = 0; i < 4; ++i) o[i] = zero;
  float m_r = -1e30f, l_r = 0.0f;

  u16* sPw = &sP[wid][0];

  // cooperative staging: 8 K-chunks + 8 V-chunks of 1KB, 2+2 per wave
  auto stage = [&](int buf, int kt) {
#pragma unroll
    for (int c = 0; c < 2; ++c) {
      const int kc = wid * 2 + c;
      // K tile rows are contiguous in Kh: 8KB straight copy
      ld_lds16(Kb + (size_t)kt * 64 + kc * 512 + lane * 8, &sK[buf][kc * 512]);
      // V^T tile: row d = kc*8+(lane>>3), cols [kt + (lane&7)*8, +8)
      ld_lds16(Vb + (size_t)(kc * 8 + (lane >> 3)) * 2048 + kt + (lane & 7) * 8,
               &sV[buf][kc * 512]);
    }
  };

  stage(0, 0);
  __syncthreads();

  for (int ki = 0; ki < nkt; ++ki) {
    const int buf = ki & 1;
    const int kt = ki * 64;
    if (ki + 1 < nkt) stage(buf ^ 1, kt + 64);  // async DMA, full tile of cover
    // ---- frag reads from LDS (issue all early; V overlaps softmax)
    bf16x8 ka0[4], ka1[4], va0[4], va1[4];
#pragma unroll
    for (int tn = 0; tn < 4; ++tn) {
      const int base = (tn * 16 + col16) * 64 + quad * 8;
      ka0[tn] = *(const bf16x8*)&sK[buf][base];
      ka1[tn] = *(const bf16x8*)&sK[buf][base + 32];
      va0[tn] = *(const bf16x8*)&sV[buf][base];
      va1[tn] = *(const bf16x8*)&sV[buf][base + 32];
    }
    // ---- S^T = K*Q^T
    f32x4 sc[4];
#pragma unroll
    for (int tn = 0; tn < 4; ++tn)
      sc[tn] = mfma16(ka1[tn], bQ1, mfma16(ka0[tn], bQ0, zero));
    // ---- scale + causal mask (only the diagonal tile)
    const bool diag = (ki == nkt - 1);
#pragma unroll
    for (int tn = 0; tn < 4; ++tn)
#pragma unroll
      for (int rr = 0; rr < 4; ++rr) {
        float v = sc[tn][rr] * 0.125f;
        if (diag && (kt + tn * 16 + quad * 4 + rr > qw + col16)) v = -1e30f;
        sc[tn][rr] = v;
      }
    // ---- row max: 15 in-lane fmax + 2 cross-quad shuffles
    float vm = sc[0][0];
#pragma unroll
    for (int tn = 0; tn < 4; ++tn)
#pragma unroll
      for (int rr = 0; rr < 4; ++rr) vm = fmaxf(vm, sc[tn][rr]);
    vm = fmaxf(vm, __shfl_xor(vm, 16, 64));
    vm = fmaxf(vm, __shfl_xor(vm, 32, 64));
    const float mn = fmaxf(m_r, vm);
    const float alpha = __expf(m_r - mn);
    m_r = mn;
    // ---- P = exp(S-m), pack pairs -> LDS P^T[qrow][kcol]
    float rs = 0.0f;
#pragma unroll
    for (int tn = 0; tn < 4; ++tn)
#pragma unroll
      for (int h2 = 0; h2 < 2; ++h2) {
        const float p0 = __expf(sc[tn][2 * h2] - mn);
        const float p1 = __expf(sc[tn][2 * h2 + 1] - mn);
        rs += p0 + p1;
        const uint32_t w = (uint32_t)f2bf(p0) | ((uint32_t)f2bf(p1) << 16);
        ((uint32_t*)sPw)[col16 * 36 + tn * 8 + quad * 2 + h2] = w;
      }
    rs += __shfl_xor(rs, 16, 64);
    rs += __shfl_xor(rs, 32, 64);
    l_r = l_r * alpha + rs;
    // ---- rescale O^T
#pragma unroll
    for (int t = 0; t < 4; ++t)
#pragma unroll
      for (int rr = 0; rr < 4; ++rr) o[t][rr] *= alpha;
    asm volatile("s_waitcnt lgkmcnt(0)" ::: "memory");  // P writes visible
    // ---- O^T += V^T * P^T
    const bf16x8 bP0 = *(const bf16x8*)(sPw + col16 * 72 + quad * 8);
    const bf16x8 bP1 = *(const bf16x8*)(sPw + col16 * 72 + 32 + quad * 8);
#pragma unroll
    for (int tn = 0; tn < 4; ++tn)
      o[tn] = mfma16(va1[tn], bP1, mfma16(va0[tn], bP0, o[tn]));
    __syncthreads();  // drains staging DMA (vmcnt) + guards buf reuse
  }

  // ---- epilogue: normalize, store O^T (lane: d = tn*16+quad*4+r, qrow = col16)
  const float invl = 1.0f / l_r;
  const size_t row = (size_t)b * 2048 + qw + col16;
#pragma unroll
  for (int tn = 0; tn < 4; ++tn)
#pragma unroll
    for (int h2 = 0; h2 < 2; ++h2) {
      const float v0 = o[tn][2 * h2] * invl;
      const float v1 = o[tn][2 * h2 + 1] * invl;
      const uint32_t w = (uint32_t)f2bf(v0) | ((uint32_t)f2bf(v1) << 16);
      const int col = h * 64 + tn * 16 + quad * 4 + 2 * h2;
      *(uint32_t*)(O + row * 768 + col) = w;
    }
}

// ---------- launch ----------
extern "C" void kernel_launch(void* const* d_in, const int* in_sizes, int n_in,
                              void* d_out, int out_size, void* d_ws, size_t ws_size,
                              hipStream_t stream) {
  const float* x       = (const float*)d_in[0];
  const int*   row_ids = (const int*)d_in[1];
  const int*   col_ids = (const int*)d_in[2];
  const float* Wq      = (const float*)d_in[3];
  const float* Wk      = (const float*)d_in[4];
  const float* Wv      = (const float*)d_in[5];
  const float* Wo      = (const float*)d_in[6];
  float* out = (float*)d_out;

  uint8_t* w8 = (uint8_t*)d_ws;
  u16* x_bf = (u16*)(w8 + 0);         // 4096x768
  u16* wqkv = (u16*)(w8 + 6291456);   // 2304x768
  u16* wo   = (u16*)(w8 + 9830400);   // 768x768
  u16* qkv  = (u16*)(w8 + 11010048);  // 4096x2304
  u16* qh   = (u16*)(w8 + 29884416);  // (24,2048,64)
  u16* kh   = (u16*)(w8 + 36175872);  // (24,2048,64)
  u16* vt   = (u16*)(w8 + 42467328);  // (24,64,2048)
  u16* obuf = (u16*)(w8 + 48758784);  // 4096x768

  // 1) convert everything to bf16 (one launch)
  k_cvt_all<<<5376, 256, 0, stream>>>(x, Wq, Wk, Wv, Wo, x_bf, wqkv, wo);
  // 2) fused QKV projection: (4096x768) @ (2304x768)^T -> bf16
  k_gemm64<false><<<dim3(18, 64), 256, 0, stream>>>(x_bf, wqkv, (void*)qkv, 2304, 768);
  // 3) RoPE(q,k) relayout + V transpose (one launch)
  k_rope_vtrans<<<6912, 256, 0, stream>>>(qkv, row_ids, col_ids, qh, kh, vt);
  // 4) causal flash attention -> bf16
  k_attn<<<768, 256, 0, stream>>>(qh, kh, vt, obuf);
  // 5) output projection -> f32
  k_gemm64<true><<<dim3(6, 64), 256, 0, stream>>>(obuf, wo, (void*)out, 768, 768);
}

// Round 4
// 205.888 us; speedup vs baseline: 1.5700x; 1.0056x over previous
//
#include <hip/hip_runtime.h>
#include <stdint.h>
#include <stddef.h>

#define DEV __device__ __forceinline__

typedef unsigned short u16;
typedef __attribute__((ext_vector_type(8))) __bf16 bf16x8;
typedef __attribute__((ext_vector_type(4))) float f32x4;
typedef __attribute__((ext_vector_type(8))) unsigned short u16x8;
typedef __attribute__((ext_vector_type(4))) unsigned short u16x4;

// ---------- helpers ----------
DEV u16 f2bf(float f) {
  uint32_t u = __builtin_bit_cast(uint32_t, f);
  u += 0x7fffu + ((u >> 16) & 1u);  // round-to-nearest-even
  return (u16)(u >> 16);
}
DEV float bf2f(u16 h) {
  uint32_t u = ((uint32_t)h) << 16;
  return __builtin_bit_cast(float, u);
}
DEV f32x4 mfma16(bf16x8 a, bf16x8 b, f32x4 c) {
  return __builtin_amdgcn_mfma_f32_16x16x32_bf16(a, b, c, 0, 0, 0);
}
DEV void ld_lds16(const void* g, void* l) {
  __builtin_amdgcn_global_load_lds((const __attribute__((address_space(1))) void*)g,
                                   (__attribute__((address_space(3))) void*)l, 16, 0, 0);
}

// ---------- f32 -> bf16 convert, all 5 tensors in one launch ----------
__global__ __launch_bounds__(256) void k_cvt_all(const float* __restrict__ x,
                                                 const float* __restrict__ wq,
                                                 const float* __restrict__ wk,
                                                 const float* __restrict__ wv,
                                                 const float* __restrict__ wo,
                                                 u16* __restrict__ dx,
                                                 u16* __restrict__ dqkv,
                                                 u16* __restrict__ dwo) {
  const int bid = blockIdx.x;
  const float* src;
  u16* dst;
  int off;
  if (bid < 3072) {
    src = x; dst = dx; off = bid;
  } else {
    const int t = bid - 3072;
    const int w = t / 576;
    off = t - w * 576;
    src = (w == 0) ? wq : (w == 1) ? wk : (w == 2) ? wv : wo;
    dst = (w < 3) ? (dqkv + (size_t)w * 589824) : dwo;
  }
  const int i = (off * 256 + threadIdx.x) * 4;
  const float4 f = *(const float4*)(src + i);
  u16x4 o;
  o.x = f2bf(f.x); o.y = f2bf(f.y); o.z = f2bf(f.z); o.w = f2bf(f.w);
  *(u16x4*)(dst + i) = o;
}

// ---------- GEMM: C[M,N] = A[M,K] * B[N,K]^T, 64x128 tile (QKV proj) ----------
template <bool OUT_F32>
__global__ __launch_bounds__(256, 4) void k_gemm64(const u16* __restrict__ A,
                                                   const u16* __restrict__ B,
                                                   void* __restrict__ Cv,
                                                   int N, int K) {
  __shared__ __align__(16) u16 sA[64 * 64];
  __shared__ __align__(16) u16 sB[128 * 64];
  const int tid = threadIdx.x;
  const int lane = tid & 63;
  const int wid = tid >> 6;
  const int col16 = lane & 15, quad = lane >> 4;
  const int rowBase = blockIdx.y * 64;
  const int colBase = blockIdx.x * 128;
  const int seg_r = lane >> 3;
  const int seg_c = lane & 7;

  f32x4 zero; zero[0] = zero[1] = zero[2] = zero[3] = 0.0f;
  f32x4 acc[4][2];
#pragma unroll
  for (int i = 0; i < 4; ++i) { acc[i][0] = zero; acc[i][1] = zero; }

  for (int k0 = 0; k0 < K; k0 += 64) {
#pragma unroll
    for (int c = 0; c < 2; ++c) {
      const int seg = wid * 2 + c;
      ld_lds16(A + (size_t)(rowBase + seg * 8 + seg_r) * K + k0 + seg_c * 8, sA + seg * 512);
    }
#pragma unroll
    for (int c = 0; c < 4; ++c) {
      const int seg = wid * 4 + c;
      ld_lds16(B + (size_t)(colBase + seg * 8 + seg_r) * K + k0 + seg_c * 8, sB + seg * 512);
    }
    __syncthreads();
#pragma unroll
    for (int kk = 0; kk < 2; ++kk) {
      bf16x8 af[4], bfr[2];
#pragma unroll
      for (int t = 0; t < 4; ++t)
        af[t] = *(const bf16x8*)(sA + (t * 16 + col16) * 64 + kk * 32 + quad * 8);
#pragma unroll
      for (int t = 0; t < 2; ++t)
        bfr[t] = *(const bf16x8*)(sB + (wid * 32 + t * 16 + col16) * 64 + kk * 32 + quad * 8);
#pragma unroll
      for (int tm = 0; tm < 4; ++tm)
#pragma unroll
        for (int tn = 0; tn < 2; ++tn)
          acc[tm][tn] = mfma16(af[tm], bfr[tn], acc[tm][tn]);
    }
    __syncthreads();
  }

#pragma unroll
  for (int tm = 0; tm < 4; ++tm)
#pragma unroll
    for (int tn = 0; tn < 2; ++tn)
#pragma unroll
      for (int r = 0; r < 4; ++r) {
        const int row = rowBase + tm * 16 + quad * 4 + r;
        const int col = colBase + wid * 32 + tn * 16 + col16;
        const float v = acc[tm][tn][r];
        if (OUT_F32) ((float*)Cv)[(size_t)row * N + col] = v;
        else         ((u16*)Cv)[(size_t)row * N + col] = f2bf(v);
      }
}

// ---------- GEMM: 64x64 tile, padded-LDS reg staging (out proj) ----------
// 2x2 waves of 32x32. Stride-72 LDS rows -> conflict-free ds_read_b128.
__global__ __launch_bounds__(256, 3) void k_gemm_o(const u16* __restrict__ A,
                                                   const u16* __restrict__ B,
                                                   float* __restrict__ C,
                                                   int N, int K) {
  __shared__ __align__(16) u16 sA[64 * 72];
  __shared__ __align__(16) u16 sB[64 * 72];
  const int tid = threadIdx.x;
  const int lane = tid & 63;
  const int wid = tid >> 6;
  const int col16 = lane & 15, quad = lane >> 4;
  const int wm = wid & 1, wn = wid >> 1;
  const int rowBase = blockIdx.y * 64;
  const int colBase = blockIdx.x * 64;
  const int sr = tid >> 3;        // 0..31
  const int sc8 = (tid & 7) * 8;  // u16 col offset

  f32x4 zero; zero[0] = zero[1] = zero[2] = zero[3] = 0.0f;
  f32x4 acc[2][2];
  acc[0][0] = zero; acc[0][1] = zero; acc[1][0] = zero; acc[1][1] = zero;

  u16x8 ar[2], br[2];
  auto gload = [&](int k0) {
    ar[0] = *(const u16x8*)(A + (size_t)(rowBase + sr) * K + k0 + sc8);
    ar[1] = *(const u16x8*)(A + (size_t)(rowBase + 32 + sr) * K + k0 + sc8);
    br[0] = *(const u16x8*)(B + (size_t)(colBase + sr) * K + k0 + sc8);
    br[1] = *(const u16x8*)(B + (size_t)(colBase + 32 + sr) * K + k0 + sc8);
  };

  gload(0);
  for (int k0 = 0; k0 < K; k0 += 64) {
    __syncthreads();  // prev-iter frag reads done
    *(u16x8*)&sA[sr * 72 + sc8] = ar[0];
    *(u16x8*)&sA[(32 + sr) * 72 + sc8] = ar[1];
    *(u16x8*)&sB[sr * 72 + sc8] = br[0];
    *(u16x8*)&sB[(32 + sr) * 72 + sc8] = br[1];
    if (k0 + 64 < K) gload(k0 + 64);
    __syncthreads();
#pragma unroll
    for (int kk = 0; kk < 2; ++kk) {
      bf16x8 af[2], bfr[2];
#pragma unroll
      for (int t = 0; t < 2; ++t) {
        af[t]  = *(const bf16x8*)&sA[(wm * 32 + t * 16 + col16) * 72 + kk * 32 + quad * 8];
        bfr[t] = *(const bf16x8*)&sB[(wn * 32 + t * 16 + col16) * 72 + kk * 32 + quad * 8];
      }
#pragma unroll
      for (int tm = 0; tm < 2; ++tm)
#pragma unroll
        for (int tn = 0; tn < 2; ++tn)
          acc[tm][tn] = mfma16(af[tm], bfr[tn], acc[tm][tn]);
    }
  }

#pragma unroll
  for (int tm = 0; tm < 2; ++tm)
#pragma unroll
    for (int tn = 0; tn < 2; ++tn)
#pragma unroll
      for (int r = 0; r < 4; ++r) {
        const int row = rowBase + wm * 32 + tm * 16 + quad * 4 + r;
        const int col = colBase + wn * 32 + tn * 16 + col16;
        C[(size_t)row * N + col] = acc[tm][tn][r];
      }
}

// ---------- fused: 2D RoPE relayout (blocks 0..6143) + V transpose (6144..6911) ----------
__global__ __launch_bounds__(256) void k_rope_vtrans(const u16* __restrict__ QKV,
                                                     const int* __restrict__ row_ids,
                                                     const int* __restrict__ col_ids,
                                                     u16* __restrict__ Qh,
                                                     u16* __restrict__ Kh,
                                                     u16* __restrict__ Vt) {
  __shared__ __align__(16) u16 tile[64][72];
  if (blockIdx.x < 6144) {
    const int t = blockIdx.x * 256 + threadIdx.x;
    const int p = t & 31;
    const int rest = t >> 5;
    const int h = rest % 12;
    const int bs = rest / 12;
    const int s = bs & 2047;
    const int b = bs >> 11;
    const int f = p & 15;
    const int hs = p >> 4;
    const int pos = hs ? col_ids[s] : row_ids[s];
    const float ang = (float)pos * expf(-(float)f * 0.5756462732485114f);
    float sn, cs;
    sincosf(ang, &sn, &cs);
    const int d1 = hs * 32 + f;
    const int d2 = d1 + 16;
    const size_t ibase = (size_t)bs * 2304 + h * 64;
    const size_t obase = (((size_t)b * 12 + h) * 2048 + s) * 64;
    {
      const float x1 = bf2f(QKV[ibase + d1]);
      const float x2 = bf2f(QKV[ibase + d2]);
      Qh[obase + d1] = f2bf(x1 * cs - x2 * sn);
      Qh[obase + d2] = f2bf(x2 * cs + x1 * sn);
    }
    {
      const float x1 = bf2f(QKV[ibase + 768 + d1]);
      const float x2 = bf2f(QKV[ibase + 768 + d2]);
      Kh[obase + d1] = f2bf(x1 * cs - x2 * sn);
      Kh[obase + d2] = f2bf(x2 * cs + x1 * sn);
    }
  } else {
    const int vb = blockIdx.x - 6144;
    const int s0 = (vb & 31) * 64;
    const int bh = vb >> 5;
    const int b = bh / 12, h = bh % 12;
    const int tid = threadIdx.x;
    const int rl = tid >> 2;
    const int cb = (tid & 3) * 16;
    const u16* src = QKV + ((size_t)b * 2048 + s0 + rl) * 2304 + 1536 + h * 64 + cb;
    const u16x8 v0 = *(const u16x8*)src;
    const u16x8 v1 = *(const u16x8*)(src + 8);
    *(u16x8*)&tile[rl][cb] = v0;
    *(u16x8*)&tile[rl][cb + 8] = v1;
    __syncthreads();
    u16x8 o0, o1;
#pragma unroll
    for (int j = 0; j < 8; ++j) {
      o0[j] = tile[cb + j][rl];
      o1[j] = tile[cb + 8 + j][rl];
    }
    u16* dst = Vt + ((size_t)bh * 64 + rl) * 2048 + s0 + cb;
    *(u16x8*)dst = o0;
    *(u16x8*)(dst + 8) = o1;
  }
}

// ---------- flash attention, causal, bf16 MFMA ----------
// Transposed-score form (S^T = K*Q^T, O^T = V^T*P^T). Block = 2 waves (128 thr),
// each wave owns 32 q-rows (two 16-row MFMA groups sharing one K/V frag set).
// K/V staged to LDS via registers into stride-72 (padded) rows -> conflict-free
// ds_read_b128. Double-buffered, one barrier per 64-wide k-tile. XCD swizzle:
// blockIdx%8 picks head group (3 heads/XCD -> KV hot in 4MB L2).
__global__ __launch_bounds__(128, 2) void k_attn(const u16* __restrict__ Qh,
                                                 const u16* __restrict__ Kh,
                                                 const u16* __restrict__ Vt,
                                                 u16* __restrict__ O) {
  __shared__ __align__(16) u16 sK[2][64 * 72];
  __shared__ __align__(16) u16 sV[2][64 * 72];
  __shared__ __align__(16) u16 sP[2][32 * 72];
  const int tid = threadIdx.x;
  const int lane = tid & 63;
  const int wid = tid >> 6;       // 0..1
  const int col16 = lane & 15;
  const int quad = lane >> 4;
  // block mapping: XCD-major, longest q-tiles first
  const int fIdx = blockIdx.x;    // 0..767
  const int b3 = fIdx & 7;
  const int r_ = fIdx >> 3;       // 0..95
  const int g_ = r_ >> 5;         // 0..2
  const int qt = 31 - (r_ & 31);
  const int bh = b3 + 8 * g_;     // 0..23
  const int b = bh / 12, h = bh % 12;
  const int qw = qt * 64 + wid * 32;  // this wave's first q-row
  const int nkt = qt + 1;             // same for both waves

  const u16* Qb = Qh + (size_t)bh * (2048 * 64);
  const u16* Kb = Kh + (size_t)bh * (2048 * 64);
  const u16* Vb = Vt + (size_t)bh * (64 * 2048);

  // staging indices: 128 threads, K tile 64x64 u16 (8KB) + V tile 8KB
  const int sr = tid >> 3;        // 0..15
  const int sc8 = (tid & 7) * 8;  // u16 chunk offset

  // Q B-frags for both groups: B[n=qrow][k=quad*8+j], two K=32 halves
  bf16x8 bQ[2][2];
#pragma unroll
  for (int g = 0; g < 2; ++g) {
    const u16* qp = Qb + (size_t)(qw + g * 16 + col16) * 64 + quad * 8;
    bQ[g][0] = *(const bf16x8*)qp;
    bQ[g][1] = *(const bf16x8*)(qp + 32);
  }

  f32x4 zero; zero[0] = zero[1] = zero[2] = zero[3] = 0.0f;
  f32x4 o[2][4];  // O^T per group: row d = tn*16+quad*4+r, col qrow = col16
#pragma unroll
  for (int g = 0; g < 2; ++g)
#pragma unroll
    for (int i = 0; i < 4; ++i) o[g][i] = zero;
  float m_r[2] = {-1e30f, -1e30f}, l_r[2] = {0.0f, 0.0f};

  u16* sPw = &sP[wid][0];

  u16x8 kr[4], vr[4];
  auto gload = [&](int kt) {
#pragma unroll
    for (int i = 0; i < 4; ++i) {
      const int row = sr + i * 16;
      kr[i] = *(const u16x8*)(Kb + (size_t)(kt + row) * 64 + sc8);
      vr[i] = *(const u16x8*)(Vb + (size_t)row * 2048 + kt + sc8);
    }
  };
  auto lwrite = [&](int buf) {
#pragma unroll
    for (int i = 0; i < 4; ++i) {
      const int row = sr + i * 16;
      *(u16x8*)&sK[buf][row * 72 + sc8] = kr[i];
      *(u16x8*)&sV[buf][row * 72 + sc8] = vr[i];
    }
  };

  gload(0);
  lwrite(0);
  if (nkt > 1) gload(64);
  __syncthreads();

  for (int ki = 0; ki < nkt; ++ki) {
    const int buf = ki & 1;
    const int kt = ki * 64;
    if (ki + 1 < nkt) {
      lwrite(buf ^ 1);                     // regs hold tile ki+1
      if (ki + 2 < nkt) gload(kt + 128);   // start loads for tile ki+2
    }
    // ---- K frags (stride-72 rows: conflict-free)
    bf16x8 ka0[4], ka1[4];
#pragma unroll
    for (int tn = 0; tn < 4; ++tn) {
      const int base = (tn * 16 + col16) * 72 + quad * 8;
      ka0[tn] = *(const bf16x8*)&sK[buf][base];
      ka1[tn] = *(const bf16x8*)&sK[buf][base + 32];
    }
    // ---- S^T = K*Q^T for both q-groups (K frags shared)
    f32x4 sc[2][4];
#pragma unroll
    for (int tn = 0; tn < 4; ++tn) {
      sc[0][tn] = mfma16(ka1[tn], bQ[0][1], mfma16(ka0[tn], bQ[0][0], zero));
      sc[1][tn] = mfma16(ka1[tn], bQ[1][1], mfma16(ka0[tn], bQ[1][0], zero));
    }
    // ---- V frags (overlap with softmax below)
    bf16x8 va0[4], va1[4];
#pragma unroll
    for (int tn = 0; tn < 4; ++tn) {
      const int base = (tn * 16 + col16) * 72 + quad * 8;
      va0[tn] = *(const bf16x8*)&sV[buf][base];
      va1[tn] = *(const bf16x8*)&sV[buf][base + 32];
    }
    // ---- per-group softmax (qrow = qw + g*16 + col16, per-lane scalar stats)
#pragma unroll
    for (int g = 0; g < 2; ++g) {
      const int qrow = qw + g * 16 + col16;
      if (kt + 63 > qw + g * 16) {
#pragma unroll
        for (int tn = 0; tn < 4; ++tn)
#pragma unroll
          for (int rr = 0; rr < 4; ++rr) {
            float v = sc[g][tn][rr] * 0.125f;
            if (kt + tn * 16 + quad * 4 + rr > qrow) v = -1e30f;
            sc[g][tn][rr] = v;
          }
      } else {
#pragma unroll
        for (int tn = 0; tn < 4; ++tn)
#pragma unroll
          for (int rr = 0; rr < 4; ++rr) sc[g][tn][rr] *= 0.125f;
      }
      float vm = sc[g][0][0];
#pragma unroll
      for (int tn = 0; tn < 4; ++tn)
#pragma unroll
        for (int rr = 0; rr < 4; ++rr) vm = fmaxf(vm, sc[g][tn][rr]);
      vm = fmaxf(vm, __shfl_xor(vm, 16, 64));
      vm = fmaxf(vm, __shfl_xor(vm, 32, 64));
      const float mn = fmaxf(m_r[g], vm);
      const float alpha = __expf(m_r[g] - mn);
      m_r[g] = mn;
      float rs = 0.0f;
#pragma unroll
      for (int tn = 0; tn < 4; ++tn)
#pragma unroll
        for (int h2 = 0; h2 < 2; ++h2) {
          const float p0 = __expf(sc[g][tn][2 * h2] - mn);
          const float p1 = __expf(sc[g][tn][2 * h2 + 1] - mn);
          rs += p0 + p1;
          const uint32_t w = (uint32_t)f2bf(p0) | ((uint32_t)f2bf(p1) << 16);
          ((uint32_t*)sPw)[(g * 16 + col16) * 36 + tn * 8 + quad * 2 + h2] = w;
        }
      rs += __shfl_xor(rs, 16, 64);
      rs += __shfl_xor(rs, 32, 64);
      l_r[g] = l_r[g] * alpha + rs;
#pragma unroll
      for (int t = 0; t < 4; ++t)
#pragma unroll
        for (int rr = 0; rr < 4; ++rr) o[g][t][rr] *= alpha;
    }
    asm volatile("s_waitcnt lgkmcnt(0)" ::: "memory");  // P writes visible to own reads
    // ---- O^T += V^T * P^T (V frags shared across groups)
#pragma unroll
    for (int g = 0; g < 2; ++g) {
      const bf16x8 bP0 = *(const bf16x8*)(sPw + (g * 16 + col16) * 72 + quad * 8);
      const bf16x8 bP1 = *(const bf16x8*)(sPw + (g * 16 + col16) * 72 + 32 + quad * 8);
#pragma unroll
      for (int tn = 0; tn < 4; ++tn)
        o[g][tn] = mfma16(va1[tn], bP1, mfma16(va0[tn], bP0, o[g][tn]));
    }
    __syncthreads();  // staged writes visible; buf safe to overwrite next iter
  }

  // ---- epilogue: normalize + store both groups
#pragma unroll
  for (int g = 0; g < 2; ++g) {
    const float invl = 1.0f / l_r[g];
    const size_t row = (size_t)b * 2048 + qw + g * 16 + col16;
#pragma unroll
    for (int tn = 0; tn < 4; ++tn)
#pragma unroll
      for (int h2 = 0; h2 < 2; ++h2) {
        const float v0 = o[g][tn][2 * h2] * invl;
        const float v1 = o[g][tn][2 * h2 + 1] * invl;
        const uint32_t w = (uint32_t)f2bf(v0) | ((uint32_t)f2bf(v1) << 16);
        const int col = h * 64 + tn * 16 + quad * 4 + 2 * h2;
        *(uint32_t*)(O + row * 768 + col) = w;
      }
  }
}

// ---------- launch ----------
extern "C" void kernel_launch(void* const* d_in, const int* in_sizes, int n_in,
                              void* d_out, int out_size, void* d_ws, size_t ws_size,
                              hipStream_t stream) {
  const float* x       = (const float*)d_in[0];
  const int*   row_ids = (const int*)d_in[1];
  const int*   col_ids = (const int*)d_in[2];
  const float* Wq      = (const float*)d_in[3];
  const float* Wk      = (const float*)d_in[4];
  const float* Wv      = (const float*)d_in[5];
  const float* Wo      = (const float*)d_in[6];
  float* out = (float*)d_out;

  uint8_t* w8 = (uint8_t*)d_ws;
  u16* x_bf = (u16*)(w8 + 0);         // 4096x768
  u16* wqkv = (u16*)(w8 + 6291456);   // 2304x768
  u16* wo   = (u16*)(w8 + 9830400);   // 768x768
  u16* qkv  = (u16*)(w8 + 11010048);  // 4096x2304
  u16* qh   = (u16*)(w8 + 29884416);  // (24,2048,64)
  u16* kh   = (u16*)(w8 + 36175872);  // (24,2048,64)
  u16* vt   = (u16*)(w8 + 42467328);  // (24,64,2048)
  u16* obuf = (u16*)(w8 + 48758784);  // 4096x768

  // 1) convert everything to bf16
  k_cvt_all<<<5376, 256, 0, stream>>>(x, Wq, Wk, Wv, Wo, x_bf, wqkv, wo);
  // 2) fused QKV projection: (4096x768) @ (2304x768)^T -> bf16
  k_gemm64<false><<<dim3(18, 64), 256, 0, stream>>>(x_bf, wqkv, (void*)qkv, 2304, 768);
  // 3) RoPE(q,k) relayout + V transpose
  k_rope_vtrans<<<6912, 256, 0, stream>>>(qkv, row_ids, col_ids, qh, kh, vt);
  // 4) causal flash attention -> bf16
  k_attn<<<768, 128, 0, stream>>>(qh, kh, vt, obuf);
  // 5) output projection -> f32
  k_gemm_o<<<dim3(12, 64), 256, 0, stream>>>(obuf, wo, out, 768, 768);
}

// Round 6
// 190.020 us; speedup vs baseline: 1.7011x; 1.0835x over previous
//
#include <hip/hip_runtime.h>
#include <stdint.h>
#include <stddef.h>

#define DEV __device__ __forceinline__

typedef unsigned short u16;
typedef __attribute__((ext_vector_type(8))) __bf16 bf16x8;
typedef __attribute__((ext_vector_type(4))) float f32x4;
typedef __attribute__((ext_vector_type(8))) unsigned short u16x8;
typedef __attribute__((ext_vector_type(4))) unsigned short u16x4;

// ---------- helpers ----------
DEV u16 f2bf(float f) {
  uint32_t u = __builtin_bit_cast(uint32_t, f);
  u += 0x7fffu + ((u >> 16) & 1u);  // round-to-nearest-even
  return (u16)(u >> 16);
}
DEV float bf2f(u16 h) {
  uint32_t u = ((uint32_t)h) << 16;
  return __builtin_bit_cast(float, u);
}
DEV f32x4 mfma16(bf16x8 a, bf16x8 b, f32x4 c) {
  return __builtin_amdgcn_mfma_f32_16x16x32_bf16(a, b, c, 0, 0, 0);
}
DEV void ld_lds16(const void* g, void* l) {
  __builtin_amdgcn_global_load_lds((const __attribute__((address_space(1))) void*)g,
                                   (__attribute__((address_space(3))) void*)l, 16, 0, 0);
}

// ---------- f32 -> bf16 convert, all 5 tensors in one launch ----------
__global__ __launch_bounds__(256) void k_cvt_all(const float* __restrict__ x,
                                                 const float* __restrict__ wq,
                                                 const float* __restrict__ wk,
                                                 const float* __restrict__ wv,
                                                 const float* __restrict__ wo,
                                                 u16* __restrict__ dx,
                                                 u16* __restrict__ dqkv,
                                                 u16* __restrict__ dwo) {
  const int bid = blockIdx.x;
  const float* src;
  u16* dst;
  int off;
  if (bid < 3072) {
    src = x; dst = dx; off = bid;
  } else {
    const int t = bid - 3072;
    const int w = t / 576;
    off = t - w * 576;
    src = (w == 0) ? wq : (w == 1) ? wk : (w == 2) ? wv : wo;
    dst = (w < 3) ? (dqkv + (size_t)w * 589824) : dwo;
  }
  const int i = (off * 256 + threadIdx.x) * 4;
  const float4 f = *(const float4*)(src + i);
  u16x4 o;
  o.x = f2bf(f.x); o.y = f2bf(f.y); o.z = f2bf(f.z); o.w = f2bf(f.w);
  *(u16x4*)(dst + i) = o;
}

// ---------- GEMM: C[M,N] = A[M,K] * B[N,K]^T, 128x128 m97 tile (QKV proj) ----------
template <bool OUT_F32>
__global__ __launch_bounds__(256) void k_gemm_bt(const u16* __restrict__ A,
                                                 const u16* __restrict__ B,
                                                 void* __restrict__ Cv,
                                                 int N, int K) {
  __shared__ __align__(16) u16 sA[128 * 64];
  __shared__ __align__(16) u16 sB[128 * 64];
  const int tid = threadIdx.x;
  const int lane = tid & 63;
  const int wid = tid >> 6;
  const int wm = wid & 1, wn = wid >> 1;
  const int col16 = lane & 15, quad = lane >> 4;
  const int rowBase = blockIdx.y * 128;
  const int colBase = blockIdx.x * 128;
  const int seg_r = lane >> 3;
  const int seg_c = lane & 7;

  f32x4 zero; zero[0] = zero[1] = zero[2] = zero[3] = 0.0f;
  f32x4 acc[4][4];
#pragma unroll
  for (int i = 0; i < 4; ++i)
#pragma unroll
    for (int j = 0; j < 4; ++j) acc[i][j] = zero;

  for (int k0 = 0; k0 < K; k0 += 64) {
#pragma unroll
    for (int c = 0; c < 4; ++c) {
      const int seg = wid * 4 + c;
      ld_lds16(A + (size_t)(rowBase + seg * 8 + seg_r) * K + k0 + seg_c * 8, sA + seg * 512);
      ld_lds16(B + (size_t)(colBase + seg * 8 + seg_r) * K + k0 + seg_c * 8, sB + seg * 512);
    }
    __syncthreads();
#pragma unroll
    for (int kk = 0; kk < 2; ++kk) {
      bf16x8 af[4], bfr[4];
#pragma unroll
      for (int t = 0; t < 4; ++t) {
        af[t]  = *(const bf16x8*)(sA + (wm * 64 + t * 16 + col16) * 64 + kk * 32 + quad * 8);
        bfr[t] = *(const bf16x8*)(sB + (wn * 64 + t * 16 + col16) * 64 + kk * 32 + quad * 8);
      }
#pragma unroll
      for (int tm = 0; tm < 4; ++tm)
#pragma unroll
        for (int tn = 0; tn < 4; ++tn)
          acc[tm][tn] = mfma16(af[tm], bfr[tn], acc[tm][tn]);
    }
    __syncthreads();
  }

#pragma unroll
  for (int tm = 0; tm < 4; ++tm)
#pragma unroll
    for (int tn = 0; tn < 4; ++tn)
#pragma unroll
      for (int r = 0; r < 4; ++r) {
        const int row = rowBase + wm * 64 + tm * 16 + quad * 4 + r;
        const int col = colBase + wn * 64 + tn * 16 + col16;
        const float v = acc[tm][tn][r];
        if (OUT_F32) ((float*)Cv)[(size_t)row * N + col] = v;
        else         ((u16*)Cv)[(size_t)row * N + col] = f2bf(v);
      }
}

// ---------- GEMM: 64x64 tile, padded-LDS reg staging (out proj) ----------
__global__ __launch_bounds__(256, 3) void k_gemm_o(const u16* __restrict__ A,
                                                   const u16* __restrict__ B,
                                                   float* __restrict__ C,
                                                   int N, int K) {
  __shared__ __align__(16) u16 sA[64 * 72];
  __shared__ __align__(16) u16 sB[64 * 72];
  const int tid = threadIdx.x;
  const int lane = tid & 63;
  const int wid = tid >> 6;
  const int col16 = lane & 15, quad = lane >> 4;
  const int wm = wid & 1, wn = wid >> 1;
  const int rowBase = blockIdx.y * 64;
  const int colBase = blockIdx.x * 64;
  const int sr = tid >> 3;
  const int sc8 = (tid & 7) * 8;

  f32x4 zero; zero[0] = zero[1] = zero[2] = zero[3] = 0.0f;
  f32x4 acc[2][2];
  acc[0][0] = zero; acc[0][1] = zero; acc[1][0] = zero; acc[1][1] = zero;

  u16x8 ar[2], br[2];
  auto gload = [&](int k0) {
    ar[0] = *(const u16x8*)(A + (size_t)(rowBase + sr) * K + k0 + sc8);
    ar[1] = *(const u16x8*)(A + (size_t)(rowBase + 32 + sr) * K + k0 + sc8);
    br[0] = *(const u16x8*)(B + (size_t)(colBase + sr) * K + k0 + sc8);
    br[1] = *(const u16x8*)(B + (size_t)(colBase + 32 + sr) * K + k0 + sc8);
  };

  gload(0);
  for (int k0 = 0; k0 < K; k0 += 64) {
    __syncthreads();
    *(u16x8*)&sA[sr * 72 + sc8] = ar[0];
    *(u16x8*)&sA[(32 + sr) * 72 + sc8] = ar[1];
    *(u16x8*)&sB[sr * 72 + sc8] = br[0];
    *(u16x8*)&sB[(32 + sr) * 72 + sc8] = br[1];
    if (k0 + 64 < K) gload(k0 + 64);
    __syncthreads();
#pragma unroll
    for (int kk = 0; kk < 2; ++kk) {
      bf16x8 af[2], bfr[2];
#pragma unroll
      for (int t = 0; t < 2; ++t) {
        af[t]  = *(const bf16x8*)&sA[(wm * 32 + t * 16 + col16) * 72 + kk * 32 + quad * 8];
        bfr[t] = *(const bf16x8*)&sB[(wn * 32 + t * 16 + col16) * 72 + kk * 32 + quad * 8];
      }
#pragma unroll
      for (int tm = 0; tm < 2; ++tm)
#pragma unroll
        for (int tn = 0; tn < 2; ++tn)
          acc[tm][tn] = mfma16(af[tm], bfr[tn], acc[tm][tn]);
    }
  }

#pragma unroll
  for (int tm = 0; tm < 2; ++tm)
#pragma unroll
    for (int tn = 0; tn < 2; ++tn)
#pragma unroll
      for (int r = 0; r < 4; ++r) {
        const int row = rowBase + wm * 32 + tm * 16 + quad * 4 + r;
        const int col = colBase + wn * 32 + tn * 16 + col16;
        C[(size_t)row * N + col] = acc[tm][tn][r];
      }
}

// ---------- fused: 2D RoPE relayout (blocks 0..6143) + V transpose (6144..6911) ----------
__global__ __launch_bounds__(256) void k_rope_vtrans(const u16* __restrict__ QKV,
                                                     const int* __restrict__ row_ids,
                                                     const int* __restrict__ col_ids,
                                                     u16* __restrict__ Qh,
                                                     u16* __restrict__ Kh,
                                                     u16* __restrict__ Vt) {
  __shared__ __align__(16) u16 tile[64][72];
  if (blockIdx.x < 6144) {
    const int t = blockIdx.x * 256 + threadIdx.x;
    const int p = t & 31;
    const int rest = t >> 5;
    const int h = rest % 12;
    const int bs = rest / 12;
    const int s = bs & 2047;
    const int b = bs >> 11;
    const int f = p & 15;
    const int hs = p >> 4;
    const int pos = hs ? col_ids[s] : row_ids[s];
    const float ang = (float)pos * expf(-(float)f * 0.5756462732485114f);
    float sn, cs;
    sincosf(ang, &sn, &cs);
    const int d1 = hs * 32 + f;
    const int d2 = d1 + 16;
    const size_t ibase = (size_t)bs * 2304 + h * 64;
    const size_t obase = (((size_t)b * 12 + h) * 2048 + s) * 64;
    {
      const float x1 = bf2f(QKV[ibase + d1]);
      const float x2 = bf2f(QKV[ibase + d2]);
      Qh[obase + d1] = f2bf(x1 * cs - x2 * sn);
      Qh[obase + d2] = f2bf(x2 * cs + x1 * sn);
    }
    {
      const float x1 = bf2f(QKV[ibase + 768 + d1]);
      const float x2 = bf2f(QKV[ibase + 768 + d2]);
      Kh[obase + d1] = f2bf(x1 * cs - x2 * sn);
      Kh[obase + d2] = f2bf(x2 * cs + x1 * sn);
    }
  } else {
    const int vb = blockIdx.x - 6144;
    const int s0 = (vb & 31) * 64;
    const int bh = vb >> 5;
    const int b = bh / 12, h = bh % 12;
    const int tid = threadIdx.x;
    const int rl = tid >> 2;
    const int cb = (tid & 3) * 16;
    const u16* src = QKV + ((size_t)b * 2048 + s0 + rl) * 2304 + 1536 + h * 64 + cb;
    const u16x8 v0 = *(const u16x8*)src;
    const u16x8 v1 = *(const u16x8*)(src + 8);
    *(u16x8*)&tile[rl][cb] = v0;
    *(u16x8*)&tile[rl][cb + 8] = v1;
    __syncthreads();
    u16x8 o0, o1;
#pragma unroll
    for (int j = 0; j < 8; ++j) {
      o0[j] = tile[cb + j][rl];
      o1[j] = tile[cb + 8 + j][rl];
    }
    u16* dst = Vt + ((size_t)bh * 64 + rl) * 2048 + s0 + cb;
    *(u16x8*)dst = o0;
    *(u16x8*)(dst + 8) = o1;
  }
}

// ---------- flash attention, causal, split-K (flash-decoding style) ----------
// Work unit = (head bh, q-tile qt of 64 rows, k-chunk of <=8 64-wide tiles).
// 1920 uniform blocks of 256 thr (4 waves x 16 q-rows). Transposed-score form.
// Single-chunk q-tiles (qt<8) write final output; others write unnormalized
// partials (bf16 O, f32 m/l) merged by k_combine.
__global__ __launch_bounds__(256, 3) void k_attn(const u16* __restrict__ Qh,
                                                 const u16* __restrict__ Kh,
                                                 const u16* __restrict__ Vt,
                                                 u16* __restrict__ O,
                                                 u16* __restrict__ Opart,
                                                 float* __restrict__ ml) {
  __shared__ __align__(16) u16 sK[2][64 * 72];
  __shared__ __align__(16) u16 sV[2][64 * 72];
  __shared__ __align__(16) u16 sP[4][16 * 72];
  const int tid = threadIdx.x;
  const int lane = tid & 63;
  const int wid = tid >> 6;
  const int col16 = lane & 15;
  const int quad = lane >> 4;
  // ---- unit decode: bx -> (bh, qt, chunk c); u enumerates (qt,c) in order
  const int bx = blockIdx.x;  // 0..1919
  const int bh = bx / 80;
  const int u = bx - bh * 80;
  int qt, c;
  if (u < 8)       { qt = u; c = 0; }
  else if (u < 24) { const int t = u - 8;  qt = 8 + (t >> 1); c = t & 1; }
  else if (u < 48) { const int t = u - 24; const int q3 = t / 3; qt = 16 + q3; c = t - q3 * 3; }
  else             { const int t = u - 48; qt = 24 + (t >> 2); c = t & 3; }
  const int nc = (qt >> 3) + 1;
  const int tile0 = c * 8;
  const int tileE = min(tile0 + 8, qt + 1);
  const int ntiles = tileE - tile0;
  const int b = bh / 12, h = bh % 12;
  const int qw = qt * 64 + wid * 16;  // this wave's first q-row

  const u16* Qb = Qh + (size_t)bh * (2048 * 64);
  const u16* Kb = Kh + (size_t)bh * (2048 * 64);
  const u16* Vb = Vt + (size_t)bh * (64 * 2048);

  // Q B-frags: B[n=qrow=col16][k=quad*8+j], two K=32 halves
  const bf16x8 bQ0 = *(const bf16x8*)(Qb + (size_t)(qw + col16) * 64 + quad * 8);
  const bf16x8 bQ1 = *(const bf16x8*)(Qb + (size_t)(qw + col16) * 64 + 32 + quad * 8);

  f32x4 zero; zero[0] = zero[1] = zero[2] = zero[3] = 0.0f;
  f32x4 o[4];  // O^T: row d = tn*16+quad*4+r, col qrow = col16
#pragma unroll
  for (int i = 0; i < 4; ++i) o[i] = zero;
  float m_r = -1e30f, l_r = 0.0f;

  u16* sPw = &sP[wid][0];

  // ---- cooperative reg staging: 256 thr, K tile 8KB + V tile 8KB, dbuf
  const int sr = tid >> 3;        // 0..31
  const int sc8 = (tid & 7) * 8;  // u16 chunk col
  u16x8 kr[2], vr[2];
  auto gload = [&](int kt) {
#pragma unroll
    for (int i = 0; i < 2; ++i) {
      kr[i] = *(const u16x8*)(Kb + (size_t)(kt + sr + i * 32) * 64 + sc8);
      vr[i] = *(const u16x8*)(Vb + (size_t)(sr + i * 32) * 2048 + kt + sc8);
    }
  };
  auto lwrite = [&](int buf) {
#pragma unroll
    for (int i = 0; i < 2; ++i) {
      *(u16x8*)&sK[buf][(sr + i * 32) * 72 + sc8] = kr[i];
      *(u16x8*)&sV[buf][(sr + i * 32) * 72 + sc8] = vr[i];
    }
  };

  gload(tile0 * 64);
  lwrite(0);
  if (ntiles > 1) gload((tile0 + 1) * 64);
  __syncthreads();

  for (int ki = 0; ki < ntiles; ++ki) {
    const int buf = ki & 1;
    const int kt = (tile0 + ki) * 64;
    if (ki + 1 < ntiles) {
      lwrite(buf ^ 1);
      if (ki + 2 < ntiles) gload((tile0 + ki + 2) * 64);
    }
    // ---- K frags (stride-72 rows)
    bf16x8 ka0[4], ka1[4];
#pragma unroll
    for (int tn = 0; tn < 4; ++tn) {
      const int base = (tn * 16 + col16) * 72 + quad * 8;
      ka0[tn] = *(const bf16x8*)&sK[buf][base];
      ka1[tn] = *(const bf16x8*)&sK[buf][base + 32];
    }
    // ---- S^T = K*Q^T  (row kcol = tn*16+quad*4+r, col qrow = col16)
    f32x4 sc[4];
#pragma unroll
    for (int tn = 0; tn < 4; ++tn)
      sc[tn] = mfma16(ka1[tn], bQ1, mfma16(ka0[tn], bQ0, zero));
    // ---- V frags (latency overlaps softmax)
    bf16x8 va0[4], va1[4];
#pragma unroll
    for (int tn = 0; tn < 4; ++tn) {
      const int base = (tn * 16 + col16) * 72 + quad * 8;
      va0[tn] = *(const bf16x8*)&sV[buf][base];
      va1[tn] = *(const bf16x8*)&sV[buf][base + 32];
    }
    // ---- scale + causal mask (wave-uniform predicate; only diagonal tile)
    if (kt + 63 > qw) {
#pragma unroll
      for (int tn = 0; tn < 4; ++tn)
#pragma unroll
        for (int rr = 0; rr < 4; ++rr) {
          float v = sc[tn][rr] * 0.125f;
          if (kt + tn * 16 + quad * 4 + rr > qw + col16) v = -1e30f;
          sc[tn][rr] = v;
        }
    } else {
#pragma unroll
      for (int tn = 0; tn < 4; ++tn)
#pragma unroll
        for (int rr = 0; rr < 4; ++rr) sc[tn][rr] *= 0.125f;
    }
    // ---- row max: 15 in-lane fmax + 2 cross-quad shuffles
    float vm = sc[0][0];
#pragma unroll
    for (int tn = 0; tn < 4; ++tn)
#pragma unroll
      for (int rr = 0; rr < 4; ++rr) vm = fmaxf(vm, sc[tn][rr]);
    vm = fmaxf(vm, __shfl_xor(vm, 16, 64));
    vm = fmaxf(vm, __shfl_xor(vm, 32, 64));
    const float mn = fmaxf(m_r, vm);
    const float alpha = __expf(m_r - mn);
    m_r = mn;
    // ---- P = exp(S-m), pack pairs -> LDS P^T[qrow][kcol]
    float rs = 0.0f;
#pragma unroll
    for (int tn = 0; tn < 4; ++tn)
#pragma unroll
      for (int h2 = 0; h2 < 2; ++h2) {
        const float p0 = __expf(sc[tn][2 * h2] - mn);
        const float p1 = __expf(sc[tn][2 * h2 + 1] - mn);
        rs += p0 + p1;
        const uint32_t w = (uint32_t)f2bf(p0) | ((uint32_t)f2bf(p1) << 16);
        ((uint32_t*)sPw)[col16 * 36 + tn * 8 + quad * 2 + h2] = w;
      }
    rs += __shfl_xor(rs, 16, 64);
    rs += __shfl_xor(rs, 32, 64);
    l_r = l_r * alpha + rs;
    // ---- rescale O^T
#pragma unroll
    for (int t = 0; t < 4; ++t)
#pragma unroll
      for (int rr = 0; rr < 4; ++rr) o[t][rr] *= alpha;
    asm volatile("s_waitcnt lgkmcnt(0)" ::: "memory");  // own P writes visible
    // ---- O^T += V^T * P^T
    const bf16x8 bP0 = *(const bf16x8*)(sPw + col16 * 72 + quad * 8);
    const bf16x8 bP1 = *(const bf16x8*)(sPw + col16 * 72 + 32 + quad * 8);
#pragma unroll
    for (int tn = 0; tn < 4; ++tn)
      o[tn] = mfma16(va1[tn], bP1, mfma16(va0[tn], bP0, o[tn]));
    __syncthreads();  // staged writes visible; buf safe next iter
  }

  if (nc == 1) {
    // ---- final: normalize + store to O
    const float invl = 1.0f / l_r;
    const size_t row = (size_t)b * 2048 + qw + col16;
#pragma unroll
    for (int tn = 0; tn < 4; ++tn)
#pragma unroll
      for (int h2 = 0; h2 < 2; ++h2) {
        const float v0 = o[tn][2 * h2] * invl;
        const float v1 = o[tn][2 * h2 + 1] * invl;
        const uint32_t w = (uint32_t)f2bf(v0) | ((uint32_t)f2bf(v1) << 16);
        const int col = h * 64 + tn * 16 + quad * 4 + 2 * h2;
        *(uint32_t*)(O + row * 768 + col) = w;
      }
  } else {
    // ---- partial: unnormalized O (bf16) + m,l (f32); slot = bx
    u16* op = Opart + (size_t)bx * 4096 + (wid * 16 + col16) * 64;
#pragma unroll
    for (int tn = 0; tn < 4; ++tn)
#pragma unroll
      for (int h2 = 0; h2 < 2; ++h2) {
        const uint32_t w = (uint32_t)f2bf(o[tn][2 * h2]) | ((uint32_t)f2bf(o[tn][2 * h2 + 1]) << 16);
        *(uint32_t*)(op + tn * 16 + quad * 4 + 2 * h2) = w;
      }
    if (quad == 0) {
      float* mlp = ml + (size_t)bx * 128;
      mlp[wid * 16 + col16] = m_r;
      mlp[64 + wid * 16 + col16] = l_r;
    }
  }
}

// ---------- combine partials for qt >= 8 ----------
// grid 576 = 24 heads x 24 q-tiles; 256 thr: row r = tid>>2, 16 d's each.
__global__ __launch_bounds__(256) void k_combine(const u16* __restrict__ Opart,
                                                 const float* __restrict__ ml,
                                                 u16* __restrict__ O) {
  const int bx = blockIdx.x;
  const int bh = bx / 24;
  const int qt = 8 + (bx - bh * 24);
  const int b = bh / 12, h = bh % 12;
  const int nc = (qt >> 3) + 1;
  const int prefix = (qt < 16) ? (8 + 2 * (qt - 8))
                   : (qt < 24) ? (24 + 3 * (qt - 16))
                               : (48 + 4 * (qt - 24));
  const int slot0 = bh * 80 + prefix;
  const int tid = threadIdx.x;
  const int r = tid >> 2;
  const int d0 = (tid & 3) * 16;

  float m_i[4], w_i[4];
  float M = -1e30f;
  for (int i = 0; i < nc; ++i) {
    m_i[i] = ml[(size_t)(slot0 + i) * 128 + r];
    M = fmaxf(M, m_i[i]);
  }
  float l = 0.0f;
  for (int i = 0; i < nc; ++i) {
    w_i[i] = __expf(m_i[i] - M);
    l += w_i[i] * ml[(size_t)(slot0 + i) * 128 + 64 + r];
  }
  const float invl = 1.0f / l;

  float a[16];
#pragma unroll
  for (int j = 0; j < 16; ++j) a[j] = 0.0f;
  for (int i = 0; i < nc; ++i) {
    const u16* op = Opart + (size_t)(slot0 + i) * 4096 + r * 64 + d0;
    const u16x8 v0 = *(const u16x8*)op;
    const u16x8 v1 = *(const u16x8*)(op + 8);
#pragma unroll
    for (int j = 0; j < 8; ++j) {
      a[j] += w_i[i] * bf2f(v0[j]);
      a[8 + j] += w_i[i] * bf2f(v1[j]);
    }
  }
  u16x8 o0, o1;
#pragma unroll
  for (int j = 0; j < 8; ++j) {
    o0[j] = f2bf(a[j] * invl);
    o1[j] = f2bf(a[8 + j] * invl);
  }
  u16* dst = O + (size_t)(b * 2048 + qt * 64 + r) * 768 + h * 64 + d0;
  *(u16x8*)dst = o0;
  *(u16x8*)(dst + 8) = o1;
}

// ---------- launch ----------
extern "C" void kernel_launch(void* const* d_in, const int* in_sizes, int n_in,
                              void* d_out, int out_size, void* d_ws, size_t ws_size,
                              hipStream_t stream) {
  const float* x       = (const float*)d_in[0];
  const int*   row_ids = (const int*)d_in[1];
  const int*   col_ids = (const int*)d_in[2];
  const float* Wq      = (const float*)d_in[3];
  const float* Wk      = (const float*)d_in[4];
  const float* Wv      = (const float*)d_in[5];
  const float* Wo      = (const float*)d_in[6];
  float* out = (float*)d_out;

  uint8_t* w8 = (uint8_t*)d_ws;
  u16* x_bf = (u16*)(w8 + 0);         // 4096x768
  u16* wqkv = (u16*)(w8 + 6291456);   // 2304x768
  u16* wo   = (u16*)(w8 + 9830400);   // 768x768
  u16* qkv  = (u16*)(w8 + 11010048);  // 4096x2304 (dead after rope_vtrans)
  u16* qh   = (u16*)(w8 + 29884416);  // (24,2048,64)
  u16* kh   = (u16*)(w8 + 36175872);  // (24,2048,64)
  u16* vt   = (u16*)(w8 + 42467328);  // (24,64,2048)
  u16* obuf = (u16*)(w8 + 48758784);  // 4096x768
  // split-K partials overlay the dead qkv region
  u16*   opart = (u16*)(w8 + 11010048);            // 1920 x 64 x 64 bf16 (15.7 MB)
  float* mlbuf = (float*)(w8 + 11010048 + 15728640);  // 1920 x 128 f32 (0.98 MB)

  // 1) convert everything to bf16
  k_cvt_all<<<5376, 256, 0, stream>>>(x, Wq, Wk, Wv, Wo, x_bf, wqkv, wo);
  // 2) fused QKV projection: (4096x768) @ (2304x768)^T -> bf16 (m97 128x128)
  k_gemm_bt<false><<<dim3(18, 32), 256, 0, stream>>>(x_bf, wqkv, (void*)qkv, 2304, 768);
  // 3) RoPE(q,k) relayout + V transpose
  k_rope_vtrans<<<6912, 256, 0, stream>>>(qkv, row_ids, col_ids, qh, kh, vt);
  // 4) causal flash attention, split-K -> partials + finals
  k_attn<<<1920, 256, 0, stream>>>(qh, kh, vt, obuf, opart, mlbuf);
  // 4b) merge partials for qt >= 8
  k_combine<<<576, 256, 0, stream>>>(opart, mlbuf, obuf);
  // 5) output projection -> f32 (grid.y = 4096/64 = 64: FIXED from round 5's 12)
  k_gemm_o<<<dim3(12, 64), 256, 0, stream>>>(obuf, wo, out, 768, 768);
}

// Round 7
// 183.966 us; speedup vs baseline: 1.7571x; 1.0329x over previous
//
#include <hip/hip_runtime.h>
#include <stdint.h>
#include <stddef.h>

#define DEV __device__ __forceinline__

typedef unsigned short u16;
typedef __attribute__((ext_vector_type(8))) __bf16 bf16x8;
typedef __attribute__((ext_vector_type(4))) float f32x4;
typedef __attribute__((ext_vector_type(8))) unsigned short u16x8;
typedef __attribute__((ext_vector_type(4))) unsigned short u16x4;

// ---------- helpers ----------
DEV u16 f2bf(float f) {
  uint32_t u = __builtin_bit_cast(uint32_t, f);
  u += 0x7fffu + ((u >> 16) & 1u);  // round-to-nearest-even
  return (u16)(u >> 16);
}
DEV float bf2f(u16 h) {
  uint32_t u = ((uint32_t)h) << 16;
  return __builtin_bit_cast(float, u);
}
DEV f32x4 mfma16(bf16x8 a, bf16x8 b, f32x4 c) {
  return __builtin_amdgcn_mfma_f32_16x16x32_bf16(a, b, c, 0, 0, 0);
}
DEV void ld_lds16(const void* g, void* l) {
  __builtin_amdgcn_global_load_lds((const __attribute__((address_space(1))) void*)g,
                                   (__attribute__((address_space(3))) void*)l, 16, 0, 0);
}

// softmax scale folded into Q: 1/sqrt(64) * log2(e)
#define Q_SCALE 0.18033688011112042f

// ---------- f32 -> bf16 convert, all 5 tensors in one launch ----------
__global__ __launch_bounds__(256) void k_cvt_all(const float* __restrict__ x,
                                                 const float* __restrict__ wq,
                                                 const float* __restrict__ wk,
                                                 const float* __restrict__ wv,
                                                 const float* __restrict__ wo,
                                                 u16* __restrict__ dx,
                                                 u16* __restrict__ dqkv,
                                                 u16* __restrict__ dwo) {
  const int bid = blockIdx.x;
  const float* src;
  u16* dst;
  int off;
  if (bid < 3072) {
    src = x; dst = dx; off = bid;
  } else {
    const int t = bid - 3072;
    const int w = t / 576;
    off = t - w * 576;
    src = (w == 0) ? wq : (w == 1) ? wk : (w == 2) ? wv : wo;
    dst = (w < 3) ? (dqkv + (size_t)w * 589824) : dwo;
  }
  const int i = (off * 256 + threadIdx.x) * 4;
  const float4 f = *(const float4*)(src + i);
  u16x4 o;
  o.x = f2bf(f.x); o.y = f2bf(f.y); o.z = f2bf(f.z); o.w = f2bf(f.w);
  *(u16x4*)(dst + i) = o;
}

// ---------- fused QKV GEMM + RoPE + head relayout + V transpose ----------
// C[4096,2304] = x_bf[4096,768] * wqkv[2304,768]^T, m97 128x128 tile.
// Epilogue (per block type = colBase/768): Q -> rope * Q_SCALE -> Qh[bh][s][d];
// K -> rope -> Kh[bh][s][d]; V -> Vt[bh][d][s]. RoPE pairs (d,d+16) are tn,tn+1
// of the same acc row -> in-lane register math. qkv intermediate never exists.
__global__ __launch_bounds__(256) void k_gemm_qkv(const u16* __restrict__ A,
                                                  const u16* __restrict__ B,
                                                  const int* __restrict__ row_ids,
                                                  const int* __restrict__ col_ids,
                                                  u16* __restrict__ Qh,
                                                  u16* __restrict__ Kh,
                                                  u16* __restrict__ Vt) {
  const int K = 768;
  __shared__ __align__(16) u16 sA[128 * 64];
  __shared__ __align__(16) u16 sB[128 * 64];
  __shared__ int sIds[256];
  const int tid = threadIdx.x;
  const int lane = tid & 63;
  const int wid = tid >> 6;
  const int wm = wid & 1, wn = wid >> 1;
  const int col16 = lane & 15, quad = lane >> 4;
  const int rowBase = blockIdx.y * 128;
  const int colBase = blockIdx.x * 128;
  const int seg_r = lane >> 3;
  const int seg_c = lane & 7;

  f32x4 zero; zero[0] = zero[1] = zero[2] = zero[3] = 0.0f;
  f32x4 acc[4][4];
#pragma unroll
  for (int i = 0; i < 4; ++i)
#pragma unroll
    for (int j = 0; j < 4; ++j) acc[i][j] = zero;

  for (int k0 = 0; k0 < K; k0 += 64) {
#pragma unroll
    for (int c = 0; c < 4; ++c) {
      const int seg = wid * 4 + c;
      ld_lds16(A + (size_t)(rowBase + seg * 8 + seg_r) * K + k0 + seg_c * 8, sA + seg * 512);
      ld_lds16(B + (size_t)(colBase + seg * 8 + seg_r) * K + k0 + seg_c * 8, sB + seg * 512);
    }
    __syncthreads();
#pragma unroll
    for (int kk = 0; kk < 2; ++kk) {
      bf16x8 af[4], bfr[4];
#pragma unroll
      for (int t = 0; t < 4; ++t) {
        af[t]  = *(const bf16x8*)(sA + (wm * 64 + t * 16 + col16) * 64 + kk * 32 + quad * 8);
        bfr[t] = *(const bf16x8*)(sB + (wn * 64 + t * 16 + col16) * 64 + kk * 32 + quad * 8);
      }
#pragma unroll
      for (int tm = 0; tm < 4; ++tm)
#pragma unroll
        for (int tn = 0; tn < 4; ++tn)
          acc[tm][tn] = mfma16(af[tm], bfr[tn], acc[tm][tn]);
    }
    __syncthreads();
  }

  // ---- epilogue
  const int bx = blockIdx.x;            // 0..17
  const int type = bx / 6;              // 0 Q, 1 K, 2 V
  const int h = (bx % 6) * 2 + wn;      // head 0..11 (each wn half = one head)
  const int bb = rowBase >> 11;
  const int s0 = rowBase & 2047;
  const size_t bh = (size_t)bb * 12 + h;

  if (type < 2) {
    if (tid < 128) {
      sIds[tid] = row_ids[s0 + tid];
      sIds[128 + tid] = col_ids[s0 + tid];
    }
    __syncthreads();
    u16* dst = (type == 0) ? Qh : Kh;
    const float scl = (type == 0) ? Q_SCALE : 1.0f;
    // inv_freq = 10000^(-col16/16) = 2^(-col16 * log2(10000)/16)
    const float invf = exp2f(-(float)col16 * 0.8304820237218406f);
#pragma unroll
    for (int tm = 0; tm < 4; ++tm)
#pragma unroll
      for (int r = 0; r < 4; ++r) {
        const int lrow = wm * 64 + tm * 16 + quad * 4 + r;
        const float aR = (float)sIds[lrow] * invf;
        const float aC = (float)sIds[128 + lrow] * invf;
        const float cR = __cosf(aR), sR = __sinf(aR);
        const float cC = __cosf(aC), sC = __sinf(aC);
        const float x1 = acc[tm][0][r], x2 = acc[tm][1][r];
        const float x3 = acc[tm][2][r], x4 = acc[tm][3][r];
        u16* p = dst + (bh * 2048 + s0 + lrow) * 64;
        p[col16]      = f2bf((x1 * cR - x2 * sR) * scl);
        p[col16 + 16] = f2bf((x2 * cR + x1 * sR) * scl);
        p[col16 + 32] = f2bf((x3 * cC - x4 * sC) * scl);
        p[col16 + 48] = f2bf((x4 * cC + x3 * sC) * scl);
      }
  } else {
#pragma unroll
    for (int tm = 0; tm < 4; ++tm)
#pragma unroll
      for (int tn = 0; tn < 4; ++tn) {
        const int d = tn * 16 + col16;
        const int srow = s0 + wm * 64 + tm * 16 + quad * 4;  // 4-aligned
        u16x4 o4;
#pragma unroll
        for (int r = 0; r < 4; ++r) o4[r] = f2bf(acc[tm][tn][r]);
        *(u16x4*)(Vt + (bh * 64 + d) * 2048 + srow) = o4;
      }
  }
}

// ---------- GEMM: 64x64 tile, padded-LDS reg staging (out proj) ----------
__global__ __launch_bounds__(256, 3) void k_gemm_o(const u16* __restrict__ A,
                                                   const u16* __restrict__ B,
                                                   float* __restrict__ C,
                                                   int N, int K) {
  __shared__ __align__(16) u16 sA[64 * 72];
  __shared__ __align__(16) u16 sB[64 * 72];
  const int tid = threadIdx.x;
  const int lane = tid & 63;
  const int wid = tid >> 6;
  const int col16 = lane & 15, quad = lane >> 4;
  const int wm = wid & 1, wn = wid >> 1;
  const int rowBase = blockIdx.y * 64;
  const int colBase = blockIdx.x * 64;
  const int sr = tid >> 3;
  const int sc8 = (tid & 7) * 8;

  f32x4 zero; zero[0] = zero[1] = zero[2] = zero[3] = 0.0f;
  f32x4 acc[2][2];
  acc[0][0] = zero; acc[0][1] = zero; acc[1][0] = zero; acc[1][1] = zero;

  u16x8 ar[2], br[2];
  auto gload = [&](int k0) {
    ar[0] = *(const u16x8*)(A + (size_t)(rowBase + sr) * K + k0 + sc8);
    ar[1] = *(const u16x8*)(A + (size_t)(rowBase + 32 + sr) * K + k0 + sc8);
    br[0] = *(const u16x8*)(B + (size_t)(colBase + sr) * K + k0 + sc8);
    br[1] = *(const u16x8*)(B + (size_t)(colBase + 32 + sr) * K + k0 + sc8);
  };

  gload(0);
  for (int k0 = 0; k0 < K; k0 += 64) {
    __syncthreads();
    *(u16x8*)&sA[sr * 72 + sc8] = ar[0];
    *(u16x8*)&sA[(32 + sr) * 72 + sc8] = ar[1];
    *(u16x8*)&sB[sr * 72 + sc8] = br[0];
    *(u16x8*)&sB[(32 + sr) * 72 + sc8] = br[1];
    if (k0 + 64 < K) gload(k0 + 64);
    __syncthreads();
#pragma unroll
    for (int kk = 0; kk < 2; ++kk) {
      bf16x8 af[2], bfr[2];
#pragma unroll
      for (int t = 0; t < 2; ++t) {
        af[t]  = *(const bf16x8*)&sA[(wm * 32 + t * 16 + col16) * 72 + kk * 32 + quad * 8];
        bfr[t] = *(const bf16x8*)&sB[(wn * 32 + t * 16 + col16) * 72 + kk * 32 + quad * 8];
      }
#pragma unroll
      for (int tm = 0; tm < 2; ++tm)
#pragma unroll
        for (int tn = 0; tn < 2; ++tn)
          acc[tm][tn] = mfma16(af[tm], bfr[tn], acc[tm][tn]);
    }
  }

#pragma unroll
  for (int tm = 0; tm < 2; ++tm)
#pragma unroll
    for (int tn = 0; tn < 2; ++tn)
#pragma unroll
      for (int r = 0; r < 4; ++r) {
        const int row = rowBase + wm * 32 + tm * 16 + quad * 4 + r;
        const int col = colBase + wn * 32 + tn * 16 + col16;
        C[(size_t)row * N + col] = acc[tm][tn][r];
      }
}

// ---------- flash attention, causal, split-K (flash-decoding style) ----------
// Scores arrive pre-scaled by 1/8*log2(e) (folded into Q) -> exp2 domain.
// Work unit = (head bh, q-tile qt of 64 rows, k-chunk of <=8 64-wide tiles).
__global__ __launch_bounds__(256, 3) void k_attn(const u16* __restrict__ Qh,
                                                 const u16* __restrict__ Kh,
                                                 const u16* __restrict__ Vt,
                                                 u16* __restrict__ O,
                                                 u16* __restrict__ Opart,
                                                 float* __restrict__ ml) {
  __shared__ __align__(16) u16 sK[2][64 * 72];
  __shared__ __align__(16) u16 sV[2][64 * 72];
  __shared__ __align__(16) u16 sP[4][16 * 72];
  const int tid = threadIdx.x;
  const int lane = tid & 63;
  const int wid = tid >> 6;
  const int col16 = lane & 15;
  const int quad = lane >> 4;
  // ---- unit decode: bx -> (bh, qt, chunk c)
  const int bx = blockIdx.x;  // 0..1919
  const int bh = bx / 80;
  const int u = bx - bh * 80;
  int qt, c;
  if (u < 8)       { qt = u; c = 0; }
  else if (u < 24) { const int t = u - 8;  qt = 8 + (t >> 1); c = t & 1; }
  else if (u < 48) { const int t = u - 24; const int q3 = t / 3; qt = 16 + q3; c = t - q3 * 3; }
  else             { const int t = u - 48; qt = 24 + (t >> 2); c = t & 3; }
  const int nc = (qt >> 3) + 1;
  const int tile0 = c * 8;
  const int tileE = min(tile0 + 8, qt + 1);
  const int ntiles = tileE - tile0;
  const int b = bh / 12, h = bh % 12;
  const int qw = qt * 64 + wid * 16;  // this wave's first q-row

  const u16* Qb = Qh + (size_t)bh * (2048 * 64);
  const u16* Kb = Kh + (size_t)bh * (2048 * 64);
  const u16* Vb = Vt + (size_t)bh * (64 * 2048);

  // Q B-frags: B[n=qrow=col16][k=quad*8+j], two K=32 halves
  const bf16x8 bQ0 = *(const bf16x8*)(Qb + (size_t)(qw + col16) * 64 + quad * 8);
  const bf16x8 bQ1 = *(const bf16x8*)(Qb + (size_t)(qw + col16) * 64 + 32 + quad * 8);

  f32x4 zero; zero[0] = zero[1] = zero[2] = zero[3] = 0.0f;
  f32x4 o[4];  // O^T: row d = tn*16+quad*4+r, col qrow = col16
#pragma unroll
  for (int i = 0; i < 4; ++i) o[i] = zero;
  float m_r = -1e30f, l_r = 0.0f;

  u16* sPw = &sP[wid][0];

  // ---- cooperative reg staging: 256 thr, K tile 8KB + V tile 8KB, dbuf
  const int sr = tid >> 3;        // 0..31
  const int sc8 = (tid & 7) * 8;  // u16 chunk col
  u16x8 kr[2], vr[2];
  auto gload = [&](int kt) {
#pragma unroll
    for (int i = 0; i < 2; ++i) {
      kr[i] = *(const u16x8*)(Kb + (size_t)(kt + sr + i * 32) * 64 + sc8);
      vr[i] = *(const u16x8*)(Vb + (size_t)(sr + i * 32) * 2048 + kt + sc8);
    }
  };
  auto lwrite = [&](int buf) {
#pragma unroll
    for (int i = 0; i < 2; ++i) {
      *(u16x8*)&sK[buf][(sr + i * 32) * 72 + sc8] = kr[i];
      *(u16x8*)&sV[buf][(sr + i * 32) * 72 + sc8] = vr[i];
    }
  };

  gload(tile0 * 64);
  lwrite(0);
  if (ntiles > 1) gload((tile0 + 1) * 64);
  __syncthreads();

  for (int ki = 0; ki < ntiles; ++ki) {
    const int buf = ki & 1;
    const int kt = (tile0 + ki) * 64;
    if (ki + 1 < ntiles) {
      lwrite(buf ^ 1);
      if (ki + 2 < ntiles) gload((tile0 + ki + 2) * 64);
    }
    // ---- K frags (stride-72 rows)
    bf16x8 ka0[4], ka1[4];
#pragma unroll
    for (int tn = 0; tn < 4; ++tn) {
      const int base = (tn * 16 + col16) * 72 + quad * 8;
      ka0[tn] = *(const bf16x8*)&sK[buf][base];
      ka1[tn] = *(const bf16x8*)&sK[buf][base + 32];
    }
    // ---- S^T = K*Q^T  (row kcol = tn*16+quad*4+r, col qrow = col16)
    f32x4 sc[4];
#pragma unroll
    for (int tn = 0; tn < 4; ++tn)
      sc[tn] = mfma16(ka1[tn], bQ1, mfma16(ka0[tn], bQ0, zero));
    // ---- V frags (latency overlaps softmax)
    bf16x8 va0[4], va1[4];
#pragma unroll
    for (int tn = 0; tn < 4; ++tn) {
      const int base = (tn * 16 + col16) * 72 + quad * 8;
      va0[tn] = *(const bf16x8*)&sV[buf][base];
      va1[tn] = *(const bf16x8*)&sV[buf][base + 32];
    }
    // ---- causal mask (scale pre-folded into Q; only diagonal tile pays)
    if (kt + 63 > qw) {
#pragma unroll
      for (int tn = 0; tn < 4; ++tn)
#pragma unroll
        for (int rr = 0; rr < 4; ++rr)
          if (kt + tn * 16 + quad * 4 + rr > qw + col16) sc[tn][rr] = -1e30f;
    }
    // ---- row max: 15 in-lane fmax + 2 cross-quad shuffles
    float vm = sc[0][0];
#pragma unroll
    for (int tn = 0; tn < 4; ++tn)
#pragma unroll
      for (int rr = 0; rr < 4; ++rr) vm = fmaxf(vm, sc[tn][rr]);
    vm = fmaxf(vm, __shfl_xor(vm, 16, 64));
    vm = fmaxf(vm, __shfl_xor(vm, 32, 64));
    const float mn = fmaxf(m_r, vm);
    const float alpha = exp2f(m_r - mn);
    m_r = mn;
    // ---- P = exp2(S-m); truncate-pack to bf16, sum rs from truncated values
    float rs = 0.0f;
#pragma unroll
    for (int tn = 0; tn < 4; ++tn)
#pragma unroll
      for (int h2 = 0; h2 < 2; ++h2) {
        const float p0 = exp2f(sc[tn][2 * h2] - mn);
        const float p1 = exp2f(sc[tn][2 * h2 + 1] - mn);
        const uint32_t u0 = __builtin_bit_cast(uint32_t, p0) & 0xffff0000u;
        const uint32_t u1 = __builtin_bit_cast(uint32_t, p1) & 0xffff0000u;
        rs += __builtin_bit_cast(float, u0) + __builtin_bit_cast(float, u1);
        ((uint32_t*)sPw)[col16 * 36 + tn * 8 + quad * 2 + h2] = u1 | (u0 >> 16);
      }
    rs += __shfl_xor(rs, 16, 64);
    rs += __shfl_xor(rs, 32, 64);
    l_r = l_r * alpha + rs;
    // ---- rescale O^T
#pragma unroll
    for (int t = 0; t < 4; ++t)
#pragma unroll
      for (int rr = 0; rr < 4; ++rr) o[t][rr] *= alpha;
    asm volatile("s_waitcnt lgkmcnt(0)" ::: "memory");  // own P writes visible
    // ---- O^T += V^T * P^T
    const bf16x8 bP0 = *(const bf16x8*)(sPw + col16 * 72 + quad * 8);
    const bf16x8 bP1 = *(const bf16x8*)(sPw + col16 * 72 + 32 + quad * 8);
#pragma unroll
    for (int tn = 0; tn < 4; ++tn)
      o[tn] = mfma16(va1[tn], bP1, mfma16(va0[tn], bP0, o[tn]));
    __syncthreads();  // staged writes visible; buf safe next iter
  }

  if (nc == 1) {
    // ---- final: normalize + store to O
    const float invl = 1.0f / l_r;
    const size_t row = (size_t)b * 2048 + qw + col16;
#pragma unroll
    for (int tn = 0; tn < 4; ++tn)
#pragma unroll
      for (int h2 = 0; h2 < 2; ++h2) {
        const float v0 = o[tn][2 * h2] * invl;
        const float v1 = o[tn][2 * h2 + 1] * invl;
        const uint32_t w = (uint32_t)f2bf(v0) | ((uint32_t)f2bf(v1) << 16);
        const int col = h * 64 + tn * 16 + quad * 4 + 2 * h2;
        *(uint32_t*)(O + row * 768 + col) = w;
      }
  } else {
    // ---- partial: unnormalized O (bf16) + m,l (f32); slot = bx
    u16* op = Opart + (size_t)bx * 4096 + (wid * 16 + col16) * 64;
#pragma unroll
    for (int tn = 0; tn < 4; ++tn)
#pragma unroll
      for (int h2 = 0; h2 < 2; ++h2) {
        const uint32_t w = (uint32_t)f2bf(o[tn][2 * h2]) | ((uint32_t)f2bf(o[tn][2 * h2 + 1]) << 16);
        *(uint32_t*)(op + tn * 16 + quad * 4 + 2 * h2) = w;
      }
    if (quad == 0) {
      float* mlp = ml + (size_t)bx * 128;
      mlp[wid * 16 + col16] = m_r;
      mlp[64 + wid * 16 + col16] = l_r;
    }
  }
}

// ---------- combine partials for qt >= 8 (m is in exp2 domain) ----------
__global__ __launch_bounds__(256) void k_combine(const u16* __restrict__ Opart,
                                                 const float* __restrict__ ml,
                                                 u16* __restrict__ O) {
  const int bx = blockIdx.x;
  const int bh = bx / 24;
  const int qt = 8 + (bx - bh * 24);
  const int b = bh / 12, h = bh % 12;
  const int nc = (qt >> 3) + 1;
  const int prefix = (qt < 16) ? (8 + 2 * (qt - 8))
                   : (qt < 24) ? (24 + 3 * (qt - 16))
                               : (48 + 4 * (qt - 24));
  const int slot0 = bh * 80 + prefix;
  const int tid = threadIdx.x;
  const int r = tid >> 2;
  const int d0 = (tid & 3) * 16;

  float m_i[4], w_i[4];
  float M = -1e30f;
  for (int i = 0; i < nc; ++i) {
    m_i[i] = ml[(size_t)(slot0 + i) * 128 + r];
    M = fmaxf(M, m_i[i]);
  }
  float l = 0.0f;
  for (int i = 0; i < nc; ++i) {
    w_i[i] = exp2f(m_i[i] - M);
    l += w_i[i] * ml[(size_t)(slot0 + i) * 128 + 64 + r];
  }
  const float invl = 1.0f / l;

  float a[16];
#pragma unroll
  for (int j = 0; j < 16; ++j) a[j] = 0.0f;
  for (int i = 0; i < nc; ++i) {
    const u16* op = Opart + (size_t)(slot0 + i) * 4096 + r * 64 + d0;
    const u16x8 v0 = *(const u16x8*)op;
    const u16x8 v1 = *(const u16x8*)(op + 8);
#pragma unroll
    for (int j = 0; j < 8; ++j) {
      a[j] += w_i[i] * bf2f(v0[j]);
      a[8 + j] += w_i[i] * bf2f(v1[j]);
    }
  }
  u16x8 o0, o1;
#pragma unroll
  for (int j = 0; j < 8; ++j) {
    o0[j] = f2bf(a[j] * invl);
    o1[j] = f2bf(a[8 + j] * invl);
  }
  u16* dst = O + (size_t)(b * 2048 + qt * 64 + r) * 768 + h * 64 + d0;
  *(u16x8*)dst = o0;
  *(u16x8*)(dst + 8) = o1;
}

// ---------- launch ----------
extern "C" void kernel_launch(void* const* d_in, const int* in_sizes, int n_in,
                              void* d_out, int out_size, void* d_ws, size_t ws_size,
                              hipStream_t stream) {
  const float* x       = (const float*)d_in[0];
  const int*   row_ids = (const int*)d_in[1];
  const int*   col_ids = (const int*)d_in[2];
  const float* Wq      = (const float*)d_in[3];
  const float* Wk      = (const float*)d_in[4];
  const float* Wv      = (const float*)d_in[5];
  const float* Wo      = (const float*)d_in[6];
  float* out = (float*)d_out;

  uint8_t* w8 = (uint8_t*)d_ws;
  u16* x_bf = (u16*)(w8 + 0);         // 4096x768
  u16* wqkv = (u16*)(w8 + 6291456);   // 2304x768
  u16* wo   = (u16*)(w8 + 9830400);   // 768x768
  u16* qh   = (u16*)(w8 + 29884416);  // (24,2048,64)
  u16* kh   = (u16*)(w8 + 36175872);  // (24,2048,64)
  u16* vt   = (u16*)(w8 + 42467328);  // (24,64,2048)
  u16* obuf = (u16*)(w8 + 48758784);  // 4096x768
  // split-K partials live in the region the old qkv intermediate used
  u16*   opart = (u16*)(w8 + 11010048);               // 1920 x 64 x 64 bf16
  float* mlbuf = (float*)(w8 + 11010048 + 15728640);  // 1920 x 128 f32

  // 1) convert everything to bf16
  k_cvt_all<<<5376, 256, 0, stream>>>(x, Wq, Wk, Wv, Wo, x_bf, wqkv, wo);
  // 2) fused QKV projection + RoPE + relayout + V transpose
  k_gemm_qkv<<<dim3(18, 32), 256, 0, stream>>>(x_bf, wqkv, row_ids, col_ids, qh, kh, vt);
  // 3) causal flash attention, split-K -> partials + finals
  k_attn<<<1920, 256, 0, stream>>>(qh, kh, vt, obuf, opart, mlbuf);
  // 3b) merge partials for qt >= 8
  k_combine<<<576, 256, 0, stream>>>(opart, mlbuf, obuf);
  // 4) output projection -> f32
  k_gemm_o<<<dim3(12, 64), 256, 0, stream>>>(obuf, wo, out, 768, 768);
}